// Round 1
// baseline (1325.489 us; speedup 1.0000x reference)
//
#include <hip/hip_runtime.h>
#include <math.h>

// MetaNETS Langevin sampler, MI355X — round 6: occupancy + full-block matvecs.
// (a) tauf aliased onto h1f: all fwd/bwd/encL2/encL3 LDS traffic is wave-private
//     (slots == w mod 4; A-frags reg-loaded before tau overwrite), so the two
//     16KB buffers share storage. LDS 40448 -> ~24.3KB => 6 blocks/CU (was 4).
// (b) drift matvecs (f1:192, f2:128, f3/gz:128 chains) k-split across all 256
//     threads (2-way input halves, partials in dsumP[768], short combine
//     phases) — halves the serial chain length that dominated step latency.
// Per block (batch elem), 4 waves; wave w owns m-tile w (points 16w..16w+15).
// fwd S2 = H1[64x128] @ Wd2[128x128] and bwd U = TAU @ Wd2^T via
// mfma_f32_16x16x32_bf16. Weights as prep-swizzled bf16 B-frag arrays in d_ws.
// launch_bounds(256,1): do NOT let the allocator force 128-VGPR spills (R3).

#define B_TOT 2048
#define NPT   64
#define ZD    64
#define HD    128

typedef short bh8 __attribute__((ext_vector_type(8)));   // 8 x bf16 (4 VGPR)
typedef float fx4 __attribute__((ext_vector_type(4)));   // MFMA C/D

__device__ __forceinline__ float sigf(float x) {
  return __builtin_amdgcn_rcpf(1.0f + __expf(-x));
}
__device__ __forceinline__ unsigned int bfb(float x) {   // fp32 -> bf16 bits (RNE)
  unsigned int u = __float_as_uint(x);
  u += 0x7FFFu + ((u >> 16) & 1u);
  return u >> 16;
}
__device__ __forceinline__ unsigned int packbf(float a, float b) {
  unsigned int ua = __float_as_uint(a), ub = __float_as_uint(b);
  ua += 0x7FFFu + ((ua >> 16) & 1u);
  ub += 0x7FFFu + ((ub >> 16) & 1u);
  return (ua >> 16) | (ub & 0xFFFF0000u);
}
__device__ __forceinline__ float wsum64(float v) {
  #pragma unroll
  for (int d = 1; d < 64; d <<= 1) v += __shfl_xor(v, d, 64);
  return v;
}
__device__ __forceinline__ void wave_sync() {   // intra-wave LDS order + drain
  __builtin_amdgcn_wave_barrier();
  __builtin_amdgcn_s_waitcnt(0xC07F);           // lgkmcnt(0)
  __builtin_amdgcn_wave_barrier();
}

// B-frag arrays (bf16): for W[K=128][N=128] with K = contraction:
//   frag[((kc*8+nt)*64 + L)*8 + j] = W[kc*32 + (L>>4)*8 + j][nt*16 + (L&15)]
// arr0: Wd2 (fwd)   arr1: Wd2^T (bwd)   arr2: We2   arr3: We3
__global__ __launch_bounds__(256)
void prep_kernel(const float* __restrict__ Wd2, const float* __restrict__ We2,
                 const float* __restrict__ We3, ushort* __restrict__ ws) {
  const int id = blockIdx.x * 256 + threadIdx.x;   // 65536 total
  const int arr = id >> 14;
  const int e = id & 16383;
  const int j = e & 7, L = (e >> 3) & 63, nt = (e >> 9) & 7, kc = e >> 12;
  const int kk = kc * 32 + (L >> 4) * 8 + j, nn = nt * 16 + (L & 15);
  float v;
  if      (arr == 0) v = Wd2[kk * HD + nn];
  else if (arr == 1) v = Wd2[nn * HD + kk];    // Wd2^T
  else if (arr == 2) v = We2[kk * HD + nn];
  else               v = We3[kk * HD + nn];
  ws[id] = (ushort)bfb(v);
}

__global__ __launch_bounds__(256, 1)
void metanets_kernel(
    const float* __restrict__ x_ctx, const float* __restrict__ y_ctx,
    const float* __restrict__ mask,  const float* __restrict__ z0,
    const float* __restrict__ noises,
    const float* __restrict__ We1, const float* __restrict__ be1,
    const float* __restrict__ be2, const float* __restrict__ be3,
    const float* __restrict__ Wd1, const float* __restrict__ bd1,
    const float* __restrict__ bd2, const float* __restrict__ Wd3,
    const float* __restrict__ bd3,
    const float* __restrict__ Wf1, const float* __restrict__ bf1,
    const float* __restrict__ Wf2, const float* __restrict__ bf2,
    const float* __restrict__ Wf3, const float* __restrict__ bf3,
    const ushort* __restrict__ wsfrag,
    float* __restrict__ out, int steps, float dt, float dco)
{
  // h1f doubles as the tau buffer: within fwd/bwd (and encL2/L3) every wave
  // only touches slots == w (mod 4), and A-frags are in registers before the
  // tau scatter overwrites those slots. Cross-wave hand-off (dec L1 -> fwd)
  // keeps its __syncthreads.
  __shared__ unsigned int h1f[4096];    // A-frag units: [(slot)*64 + lane] x 4 dw
  __shared__ float zsh[64];
  __shared__ float zw1[128];
  __shared__ float rsh[128];
  __shared__ float dsumP[768];          // [0,512): bwd partials / reused scratch
                                        // [512,768): f1 k-split partials
  __shared__ float dsumC[128];
  __shared__ float f1sh[128];           // be2 staging, then drift hidden1
  __shared__ float f2sh[128];           // be3 staging, then drift hidden2
  __shared__ float bd2sh[128], wd3sh[128], wx0sh[128], wx1sh[128];

  const int tid = threadIdx.x;
  const int lane = tid & 63;                                  // context point
  const int w = __builtin_amdgcn_readfirstlane(tid >> 6);     // wave = m-tile
  const int b = blockIdx.x;
  const int rr = lane & 15, qq = lane >> 4;

  const bh8* Wd2f  = (const bh8*)(wsfrag);
  const bh8* Wd2Tf = (const bh8*)(wsfrag + 16384);
  const bh8* We2f  = (const bh8*)(wsfrag + 32768);
  const bh8* We3f  = (const bh8*)(wsfrag + 49152);

  const float x0v = x_ctx[(b*NPT + lane)*2 + 0];
  const float x1v = x_ctx[(b*NPT + lane)*2 + 1];
  const float yv  = y_ctx[b*NPT + lane];
  const float mkv = mask[b*NPT + lane];
  const float inv_msum = 1.0f / fmaxf(wsum64(mkv), 1e-6f);
  const float bd3v = bd3[0];

  // per-lane data for the 4 C-rows this lane holds (points 16w+4*qq+g)
  float x0q[4], x1q[4], yq[4], mkq[4];
  #pragma unroll
  for (int g = 0; g < 4; ++g) {
    const int src = (w << 4) | (qq << 2) | g;
    x0q[g] = __shfl(x0v, src, 64);
    x1q[g] = __shfl(x1v, src, 64);
    yq[g]  = __shfl(yv,  src, 64);
    mkq[g] = __shfl(mkv, src, 64);
  }

  if (tid < 64) zsh[tid] = z0[b*ZD + tid];
  if (tid < 128) {
    bd2sh[tid] = bd2[tid];
    wd3sh[tid] = Wd3[tid];
    wx0sh[tid] = Wd1[64*HD + tid];
    wx1sh[tid] = Wd1[65*HD + tid];
    f1sh[tid]  = be2[tid];
    f2sh[tid]  = be3[tid];
  }
  __syncthreads();

  // ================= encoder =================
  // enc L1: lane=point, wave w computes k-slice kc=w, writes A-frag layout
  #pragma unroll
  for (int quad = 0; quad < 4; ++quad) {
    unsigned int pw[4];
    #pragma unroll
    for (int jj = 0; jj < 8; jj += 2) {
      const int k = 32*w + 8*quad + jj;
      const float sA = be1[k]   + x0v*We1[k]   + x1v*We1[HD+k]   + yv*We1[2*HD+k];
      const float sB = be1[k+1] + x0v*We1[k+1] + x1v*We1[HD+k+1] + yv*We1[2*HD+k+1];
      pw[jj>>1] = packbf(sA*sigf(sA), sB*sigf(sB));
    }
    uint4 v4; v4.x = pw[0]; v4.y = pw[1]; v4.z = pw[2]; v4.w = pw[3];
    ((uint4*)h1f)[(w*4 + (lane>>4))*64 + quad*16 + (lane&15)] = v4;
  }
  __syncthreads();

  // enc L2 (MFMA): H2 = silu(H1 @ We2 + be2) -> tau (A-frag layout, in h1f)
  {
    bh8 af[4];
    #pragma unroll
    for (int kc = 0; kc < 4; ++kc)
      af[kc] = ((const bh8*)h1f)[(kc*4 + w)*64 + lane];
    #pragma unroll 1
    for (int half = 0; half < 2; ++half) {
      const int h4 = half*4;
      fx4 acc[4];
      #pragma unroll
      for (int i = 0; i < 4; ++i) {
        const float bv = f1sh[(h4+i)*16 + rr];
        acc[i] = (fx4){bv, bv, bv, bv};
      }
      #pragma unroll
      for (int i = 0; i < 4; ++i) {
        const int nt = h4 + i;
        const bh8 b0 = We2f[(0*8+nt)*64 + lane];
        const bh8 b1 = We2f[(1*8+nt)*64 + lane];
        const bh8 b2 = We2f[(2*8+nt)*64 + lane];
        const bh8 b3 = We2f[(3*8+nt)*64 + lane];
        acc[i] = __builtin_amdgcn_mfma_f32_16x16x32_bf16(af[0], b0, acc[i], 0,0,0);
        acc[i] = __builtin_amdgcn_mfma_f32_16x16x32_bf16(af[1], b1, acc[i], 0,0,0);
        acc[i] = __builtin_amdgcn_mfma_f32_16x16x32_bf16(af[2], b2, acc[i], 0,0,0);
        acc[i] = __builtin_amdgcn_mfma_f32_16x16x32_bf16(af[3], b3, acc[i], 0,0,0);
      }
      #pragma unroll
      for (int i = 0; i < 4; ++i) {
        const int nt = h4 + i;
        #pragma unroll
        for (int g = 0; g < 4; ++g) {
          const float s2 = acc[i][g];
          const unsigned int tb = bfb(s2 * sigf(s2));
          const unsigned int pb = (unsigned int)__shfl_xor((int)tb, 1, 64);
          if ((rr & 1) == 0) {
            const int unit = ((nt>>1)*4 + w)*64 + (2*(nt&1) + (rr>>3))*16 + 4*qq + g;
            h1f[unit*4 + ((rr&7)>>1)] = tb | (pb << 16);
          }
        }
      }
    }
  }
  wave_sync();

  // enc L3 (MFMA) + masked mean-pool -> rsh
  {
    bh8 tf4[4];
    #pragma unroll
    for (int kc = 0; kc < 4; ++kc)
      tf4[kc] = ((const bh8*)h1f)[(kc*4 + w)*64 + lane];
    #pragma unroll 1
    for (int half = 0; half < 2; ++half) {
      const int h4 = half*4;
      fx4 acc[4];
      #pragma unroll
      for (int i = 0; i < 4; ++i) {
        const float bv = f2sh[(h4+i)*16 + rr];
        acc[i] = (fx4){bv, bv, bv, bv};
      }
      #pragma unroll
      for (int i = 0; i < 4; ++i) {
        const int nt = h4 + i;
        const bh8 b0 = We3f[(0*8+nt)*64 + lane];
        const bh8 b1 = We3f[(1*8+nt)*64 + lane];
        const bh8 b2 = We3f[(2*8+nt)*64 + lane];
        const bh8 b3 = We3f[(3*8+nt)*64 + lane];
        acc[i] = __builtin_amdgcn_mfma_f32_16x16x32_bf16(tf4[0], b0, acc[i], 0,0,0);
        acc[i] = __builtin_amdgcn_mfma_f32_16x16x32_bf16(tf4[1], b1, acc[i], 0,0,0);
        acc[i] = __builtin_amdgcn_mfma_f32_16x16x32_bf16(tf4[2], b2, acc[i], 0,0,0);
        acc[i] = __builtin_amdgcn_mfma_f32_16x16x32_bf16(tf4[3], b3, acc[i], 0,0,0);
      }
      #pragma unroll
      for (int i = 0; i < 4; ++i) {
        float pv = mkq[0]*acc[i][0] + mkq[1]*acc[i][1]
                 + mkq[2]*acc[i][2] + mkq[3]*acc[i][3];
        pv += __shfl_xor(pv, 16, 64);
        pv += __shfl_xor(pv, 32, 64);
        if (lane < 16) dsumP[w*128 + (h4+i)*16 + lane] = pv;
      }
    }
  }
  __syncthreads();
  if (tid < 128)
    rsh[tid] = (dsumP[tid] + dsumP[128+tid] + dsumP[256+tid] + dsumP[384+tid]) * inv_msum;
  __syncthreads();

  // ================= Langevin step loop =================
  for (int st = 0; st < steps; ++st) {
    const float t = (float)st * dt;

    // zW1[k] = bd1[k] + sum_j z[j] Wd1[j,k]
    if (tid < 128) {
      float p0 = bd1[tid], p1 = 0.f, p2 = 0.f, p3 = 0.f;
      #pragma unroll 4
      for (int j = 0; j < 64; j += 4) {
        p0 = fmaf(zsh[j+0], Wd1[(j+0)*HD + tid], p0);
        p1 = fmaf(zsh[j+1], Wd1[(j+1)*HD + tid], p1);
        p2 = fmaf(zsh[j+2], Wd1[(j+2)*HD + tid], p2);
        p3 = fmaf(zsh[j+3], Wd1[(j+3)*HD + tid], p3);
      }
      zw1[tid] = (p0+p1) + (p2+p3);
    }
    __syncthreads();

    // dec L1: h1 = silu(zW1 + x*Wd1x) -> h1f (A-frag layout, kc=w slice)
    #pragma unroll
    for (int quad = 0; quad < 4; ++quad) {
      unsigned int pw[4];
      #pragma unroll
      for (int jj = 0; jj < 8; jj += 2) {
        const int k = 32*w + 8*quad + jj;
        const float sA = zw1[k]   + x0v*wx0sh[k]   + x1v*wx1sh[k];
        const float sB = zw1[k+1] + x0v*wx0sh[k+1] + x1v*wx1sh[k+1];
        pw[jj>>1] = packbf(sA*sigf(sA), sB*sigf(sB));
      }
      uint4 v4; v4.x = pw[0]; v4.y = pw[1]; v4.z = pw[2]; v4.w = pw[3];
      ((uint4*)h1f)[(w*4 + (lane>>4))*64 + quad*16 + (lane&15)] = v4;
    }
    __syncthreads();

    // fwd (MFMA): S2 = H1 @ Wd2 + bd2; emit tau (-> h1f, wave-private slots)
    float ebw[4];
    {
      bh8 af[4];
      #pragma unroll
      for (int kc = 0; kc < 4; ++kc)
        af[kc] = ((const bh8*)h1f)[(kc*4 + w)*64 + lane];
      float da[4] = {0.f, 0.f, 0.f, 0.f};
      #pragma unroll 1
      for (int half = 0; half < 2; ++half) {
        const int h4 = half*4;
        fx4 acc[4];
        #pragma unroll
        for (int i = 0; i < 4; ++i) {
          const float bv = bd2sh[(h4+i)*16 + rr];
          acc[i] = (fx4){bv, bv, bv, bv};
        }
        #pragma unroll
        for (int i = 0; i < 4; ++i) {
          const int nt = h4 + i;
          const bh8 b0 = Wd2f[(0*8+nt)*64 + lane];
          const bh8 b1 = Wd2f[(1*8+nt)*64 + lane];
          const bh8 b2 = Wd2f[(2*8+nt)*64 + lane];
          const bh8 b3 = Wd2f[(3*8+nt)*64 + lane];
          acc[i] = __builtin_amdgcn_mfma_f32_16x16x32_bf16(af[0], b0, acc[i], 0,0,0);
          acc[i] = __builtin_amdgcn_mfma_f32_16x16x32_bf16(af[1], b1, acc[i], 0,0,0);
          acc[i] = __builtin_amdgcn_mfma_f32_16x16x32_bf16(af[2], b2, acc[i], 0,0,0);
          acc[i] = __builtin_amdgcn_mfma_f32_16x16x32_bf16(af[3], b3, acc[i], 0,0,0);
        }
        #pragma unroll
        for (int i = 0; i < 4; ++i) {
          const int nt = h4 + i;
          const float w3 = wd3sh[nt*16 + rr];
          #pragma unroll
          for (int g = 0; g < 4; ++g) {
            const float s2 = acc[i][g];
            const float sg = sigf(s2);
            da[g] = fmaf(s2*sg, w3, da[g]);
            const unsigned int tb = bfb(w3 * (sg * fmaf(s2, 1.0f - sg, 1.0f)));
            const unsigned int pb = (unsigned int)__shfl_xor((int)tb, 1, 64);
            if ((rr & 1) == 0) {
              const int unit = ((nt>>1)*4 + w)*64 + (2*(nt&1) + (rr>>3))*16 + 4*qq + g;
              h1f[unit*4 + ((rr&7)>>1)] = tb | (pb << 16);
            }
          }
        }
      }
      #pragma unroll
      for (int g = 0; g < 4; ++g) {
        float v = da[g];
        v += __shfl_xor(v, 1, 64);
        v += __shfl_xor(v, 2, 64);
        v += __shfl_xor(v, 4, 64);
        v += __shfl_xor(v, 8, 64);
        ebw[g] = t * mkq[g] * (v + bd3v - yq[g]);
      }
    }
    wave_sync();

    // bwd (MFMA): U = TAU @ Wd2^T; dsum[k] = colsum(ebw * silu'(s1) * U)
    {
      bh8 tf4[4];
      #pragma unroll
      for (int kc = 0; kc < 4; ++kc)
        tf4[kc] = ((const bh8*)h1f)[(kc*4 + w)*64 + lane];
      #pragma unroll 1
      for (int half = 0; half < 2; ++half) {
        const int h4 = half*4;
        fx4 u[4];
        #pragma unroll
        for (int i = 0; i < 4; ++i) u[i] = (fx4){0.f, 0.f, 0.f, 0.f};
        #pragma unroll
        for (int i = 0; i < 4; ++i) {
          const int nt = h4 + i;
          const bh8 b0 = Wd2Tf[(0*8+nt)*64 + lane];
          const bh8 b1 = Wd2Tf[(1*8+nt)*64 + lane];
          const bh8 b2 = Wd2Tf[(2*8+nt)*64 + lane];
          const bh8 b3 = Wd2Tf[(3*8+nt)*64 + lane];
          u[i] = __builtin_amdgcn_mfma_f32_16x16x32_bf16(tf4[0], b0, u[i], 0,0,0);
          u[i] = __builtin_amdgcn_mfma_f32_16x16x32_bf16(tf4[1], b1, u[i], 0,0,0);
          u[i] = __builtin_amdgcn_mfma_f32_16x16x32_bf16(tf4[2], b2, u[i], 0,0,0);
          u[i] = __builtin_amdgcn_mfma_f32_16x16x32_bf16(tf4[3], b3, u[i], 0,0,0);
        }
        #pragma unroll
        for (int i = 0; i < 4; ++i) {
          const int nt = h4 + i;
          const float zv = zw1[nt*16 + rr];
          const float wa = wx0sh[nt*16 + rr];
          const float wb = wx1sh[nt*16 + rr];
          float snt = 0.f;
          #pragma unroll
          for (int g = 0; g < 4; ++g) {
            const float s1 = zv + x0q[g]*wa + x1q[g]*wb;
            const float sg = sigf(s1);
            snt += ebw[g] * (sg * fmaf(s1, 1.0f - sg, 1.0f)) * u[i][g];
          }
          snt += __shfl_xor(snt, 16, 64);
          snt += __shfl_xor(snt, 32, 64);
          if (lane < 16) dsumP[w*128 + nt*16 + lane] = snt;
        }
      }
    }
    __syncthreads();

    // phase A: dsumC combine (tid<128) + f1 partials (all 256, 2-way k-split)
    {
      const int o = tid & 127;
      if (tid < 128) {
        dsumC[o] = dsumP[o] + dsumP[128+o] + dsumP[256+o] + dsumP[384+o];
        float p0 = 0.f, p1 = 0.f, p2 = 0.f, p3 = 0.f;
        #pragma unroll 4
        for (int j = 0; j < 64; j += 4) {
          p0 = fmaf(zsh[j+0], Wf1[(j+0)*HD + o], p0);
          p1 = fmaf(zsh[j+1], Wf1[(j+1)*HD + o], p1);
          p2 = fmaf(zsh[j+2], Wf1[(j+2)*HD + o], p2);
          p3 = fmaf(zsh[j+3], Wf1[(j+3)*HD + o], p3);
        }
        #pragma unroll 4
        for (int j = 0; j < 32; j += 4) {
          p0 = fmaf(rsh[j+0], Wf1[(64+j+0)*HD + o], p0);
          p1 = fmaf(rsh[j+1], Wf1[(64+j+1)*HD + o], p1);
          p2 = fmaf(rsh[j+2], Wf1[(64+j+2)*HD + o], p2);
          p3 = fmaf(rsh[j+3], Wf1[(64+j+3)*HD + o], p3);
        }
        dsumP[512 + o] = (p0+p1) + (p2+p3);
      } else {
        float p0 = fmaf(t, Wf1[192*HD + o], bf1[o]);
        float p1 = 0.f, p2 = 0.f, p3 = 0.f;
        #pragma unroll 4
        for (int j = 32; j < 128; j += 4) {
          p0 = fmaf(rsh[j+0], Wf1[(64+j+0)*HD + o], p0);
          p1 = fmaf(rsh[j+1], Wf1[(64+j+1)*HD + o], p1);
          p2 = fmaf(rsh[j+2], Wf1[(64+j+2)*HD + o], p2);
          p3 = fmaf(rsh[j+3], Wf1[(64+j+3)*HD + o], p3);
        }
        dsumP[640 + o] = (p0+p1) + (p2+p3);
      }
    }
    __syncthreads();

    // phase B: f1 combine + silu
    if (tid < 128) {
      const float a = dsumP[512 + tid] + dsumP[640 + tid];
      f1sh[tid] = a * sigf(a);
    }
    __syncthreads();

    // phase C: f2 partials (all 256, 2-way k-split) -> dsumP[0..256)
    {
      const int o = tid & 127;
      const int j0 = (tid >> 7) * 64;
      float p0 = (tid < 128) ? bf2[o] : 0.f;
      float p1 = 0.f, p2 = 0.f, p3 = 0.f;
      #pragma unroll 4
      for (int j = 0; j < 64; j += 4) {
        p0 = fmaf(f1sh[j0+j+0], Wf2[(j0+j+0)*HD + o], p0);
        p1 = fmaf(f1sh[j0+j+1], Wf2[(j0+j+1)*HD + o], p1);
        p2 = fmaf(f1sh[j0+j+2], Wf2[(j0+j+2)*HD + o], p2);
        p3 = fmaf(f1sh[j0+j+3], Wf2[(j0+j+3)*HD + o], p3);
      }
      dsumP[(tid >> 7)*128 + o] = (p0+p1) + (p2+p3);
    }
    __syncthreads();

    // phase D: f2 combine + silu
    if (tid < 128) {
      const float a = dsumP[tid] + dsumP[128 + tid];
      f2sh[tid] = a * sigf(a);
    }
    __syncthreads();

    // phase E: f3 (drift out) and gz (dec-grad) partials, 4 groups of 64
    {
      const int grp = tid >> 6, j = tid & 63;
      float p0, p1 = 0.f, p2 = 0.f, p3 = 0.f;
      if (grp < 2) {
        const int h0 = grp * 64;
        p0 = (grp == 0) ? bf3[j] : 0.f;
        #pragma unroll 4
        for (int h = 0; h < 64; h += 4) {
          p0 = fmaf(f2sh[h0+h+0], Wf3[(h0+h+0)*ZD + j], p0);
          p1 = fmaf(f2sh[h0+h+1], Wf3[(h0+h+1)*ZD + j], p1);
          p2 = fmaf(f2sh[h0+h+2], Wf3[(h0+h+2)*ZD + j], p2);
          p3 = fmaf(f2sh[h0+h+3], Wf3[(h0+h+3)*ZD + j], p3);
        }
      } else {
        const int h0 = (grp - 2) * 64;
        p0 = 0.f;
        #pragma unroll 4
        for (int h = 0; h < 64; h += 4) {
          p0 = fmaf(dsumC[h0+h+0], Wd1[j*HD + h0+h+0], p0);
          p1 = fmaf(dsumC[h0+h+1], Wd1[j*HD + h0+h+1], p1);
          p2 = fmaf(dsumC[h0+h+2], Wd1[j*HD + h0+h+2], p2);
          p3 = fmaf(dsumC[h0+h+3], Wd1[j*HD + h0+h+3], p3);
        }
      }
      dsumP[grp*64 + j] = (p0+p1) + (p2+p3);
    }
    __syncthreads();

    // phase F: combine + z update (t folded into ebw)
    if (tid < 64) {
      const float bdrift = dsumP[tid]       + dsumP[64 + tid];
      const float gz     = dsumP[128 + tid] + dsumP[192 + tid];
      const float zold = zsh[tid];
      float g = zold + gz;
      g = fminf(fmaxf(g, -100.0f), 100.0f);
      zsh[tid] = zold + (bdrift - g) * dt
               + dco * noises[(size_t)st * (B_TOT * ZD) + b * ZD + tid];
    }
    __syncthreads();
  }

  if (tid < 64) out[b * ZD + tid] = zsh[tid];
}

extern "C" void kernel_launch(void* const* d_in, const int* in_sizes, int n_in,
                              void* d_out, int out_size, void* d_ws, size_t ws_size,
                              hipStream_t stream) {
  const float* x_ctx  = (const float*)d_in[0];
  const float* y_ctx  = (const float*)d_in[1];
  const float* mask   = (const float*)d_in[2];
  const float* z0     = (const float*)d_in[3];
  const float* noises = (const float*)d_in[4];
  const float* We1 = (const float*)d_in[5];  const float* be1 = (const float*)d_in[6];
  const float* We2 = (const float*)d_in[7];  const float* be2 = (const float*)d_in[8];
  const float* We3 = (const float*)d_in[9];  const float* be3 = (const float*)d_in[10];
  const float* Wd1 = (const float*)d_in[11]; const float* bd1 = (const float*)d_in[12];
  const float* Wd2 = (const float*)d_in[13]; const float* bd2 = (const float*)d_in[14];
  const float* Wd3 = (const float*)d_in[15]; const float* bd3 = (const float*)d_in[16];
  const float* Wf1 = (const float*)d_in[17]; const float* bf1 = (const float*)d_in[18];
  const float* Wf2 = (const float*)d_in[19]; const float* bf2 = (const float*)d_in[20];
  const float* Wf3 = (const float*)d_in[21]; const float* bf3 = (const float*)d_in[22];

  const int steps = in_sizes[4] / (B_TOT * ZD);
  const float dt  = 1.0f / (float)steps;
  const float dco = (float)sqrt(2.0 / (double)steps);

  ushort* wsu = (ushort*)d_ws;   // 4 bf16 frag arrays, 128 KB total

  hipLaunchKernelGGL(prep_kernel, dim3(256), dim3(256), 0, stream, Wd2, We2, We3, wsu);
  hipLaunchKernelGGL(metanets_kernel, dim3(B_TOT), dim3(256), 0, stream,
      x_ctx, y_ctx, mask, z0, noises,
      We1, be1, be2, be3,
      Wd1, bd1, bd2, Wd3, bd3,
      Wf1, bf1, Wf2, bf2, Wf3, bf3,
      wsu, (float*)d_out, steps, dt, dco);
}

// Round 2
// 1192.395 us; speedup vs baseline: 1.1116x; 1.1116x over previous
//
#include <hip/hip_runtime.h>
#include <math.h>

// MetaNETS Langevin sampler, MI355X — round 7: round-5 structure + tauf/h1f
// aliasing ONLY. R6 post-mortem: the k-split drift phases bloated VGPR 80->112,
// capping occupancy at the same 16 waves/CU the LDS used to; net regression.
// This round keeps the round-5 code (80 VGPR) and only merges the tau buffer
// into h1f: within fwd/bwd (and encL2/L3) every wave touches only slots
// == w (mod 4), and A-frags are reg-loaded before the tau scatter overwrites
// them, so the two 16KB buffers can share storage. LDS 40448 -> 24576
// => 6 blocks/CU (was 4), 24 waves/CU theoretical.
// Per block (batch elem), 4 waves; wave w owns m-tile w (points 16w..16w+15).
// fwd S2 = H1[64x128] @ Wd2[128x128] and bwd U = TAU @ Wd2^T via
// mfma_f32_16x16x32_bf16 (32 MFMA each per wave). Weights as prep-swizzled
// bf16 B-frag arrays in d_ws (L2-resident).
// launch_bounds(256,1): do NOT let the allocator force spills (R3).

#define B_TOT 2048
#define NPT   64
#define ZD    64
#define HD    128

typedef short bh8 __attribute__((ext_vector_type(8)));   // 8 x bf16 (4 VGPR)
typedef float fx4 __attribute__((ext_vector_type(4)));   // MFMA C/D

__device__ __forceinline__ float sigf(float x) {
  return __builtin_amdgcn_rcpf(1.0f + __expf(-x));
}
__device__ __forceinline__ unsigned int bfb(float x) {   // fp32 -> bf16 bits (RNE)
  unsigned int u = __float_as_uint(x);
  u += 0x7FFFu + ((u >> 16) & 1u);
  return u >> 16;
}
__device__ __forceinline__ unsigned int packbf(float a, float b) {
  unsigned int ua = __float_as_uint(a), ub = __float_as_uint(b);
  ua += 0x7FFFu + ((ua >> 16) & 1u);
  ub += 0x7FFFu + ((ub >> 16) & 1u);
  return (ua >> 16) | (ub & 0xFFFF0000u);
}
__device__ __forceinline__ float wsum64(float v) {
  #pragma unroll
  for (int d = 1; d < 64; d <<= 1) v += __shfl_xor(v, d, 64);
  return v;
}
__device__ __forceinline__ void wave_sync() {   // intra-wave LDS order + drain
  __builtin_amdgcn_wave_barrier();
  __builtin_amdgcn_s_waitcnt(0xC07F);           // lgkmcnt(0)
  __builtin_amdgcn_wave_barrier();
}

// B-frag arrays (bf16): for W[K=128][N=128] with K = contraction:
//   frag[((kc*8+nt)*64 + L)*8 + j] = W[kc*32 + (L>>4)*8 + j][nt*16 + (L&15)]
// arr0: Wd2 (fwd)   arr1: Wd2^T (bwd)   arr2: We2   arr3: We3
__global__ __launch_bounds__(256)
void prep_kernel(const float* __restrict__ Wd2, const float* __restrict__ We2,
                 const float* __restrict__ We3, ushort* __restrict__ ws) {
  const int id = blockIdx.x * 256 + threadIdx.x;   // 65536 total
  const int arr = id >> 14;
  const int e = id & 16383;
  const int j = e & 7, L = (e >> 3) & 63, nt = (e >> 9) & 7, kc = e >> 12;
  const int kk = kc * 32 + (L >> 4) * 8 + j, nn = nt * 16 + (L & 15);
  float v;
  if      (arr == 0) v = Wd2[kk * HD + nn];
  else if (arr == 1) v = Wd2[nn * HD + kk];    // Wd2^T
  else if (arr == 2) v = We2[kk * HD + nn];
  else               v = We3[kk * HD + nn];
  ws[id] = (ushort)bfb(v);
}

__global__ __launch_bounds__(256, 1)
void metanets_kernel(
    const float* __restrict__ x_ctx, const float* __restrict__ y_ctx,
    const float* __restrict__ mask,  const float* __restrict__ z0,
    const float* __restrict__ noises,
    const float* __restrict__ We1, const float* __restrict__ be1,
    const float* __restrict__ be2, const float* __restrict__ be3,
    const float* __restrict__ Wd1, const float* __restrict__ bd1,
    const float* __restrict__ bd2, const float* __restrict__ Wd3,
    const float* __restrict__ bd3,
    const float* __restrict__ Wf1, const float* __restrict__ bf1,
    const float* __restrict__ Wf2, const float* __restrict__ bf2,
    const float* __restrict__ Wf3, const float* __restrict__ bf3,
    const ushort* __restrict__ wsfrag,
    float* __restrict__ out, int steps, float dt, float dco)
{
  // h1f doubles as the tau buffer (see header comment). Cross-wave hand-offs
  // (enc L1 -> enc L2, dec L1 -> fwd) keep their __syncthreads; fwd->bwd and
  // encL2->encL3 traffic is wave-private mod-4-disjoint (wave_sync only).
  __shared__ unsigned int h1f[4096];    // A-frag units: [(slot)*64 + lane] x 4 dw
  __shared__ float zsh[64];
  __shared__ float zw1[128];
  __shared__ float rsh[128];
  __shared__ float dsumP[512];
  __shared__ float dsumC[128];
  __shared__ float f1sh[128];           // be2 staging, then drift hidden1
  __shared__ float f2sh[128];           // be3 staging, then drift hidden2
  __shared__ float bgz[128];
  __shared__ float bd2sh[128], wd3sh[128], wx0sh[128], wx1sh[128];

  const int tid = threadIdx.x;
  const int lane = tid & 63;                                  // context point
  const int w = __builtin_amdgcn_readfirstlane(tid >> 6);     // wave = m-tile
  const int b = blockIdx.x;
  const int rr = lane & 15, qq = lane >> 4;

  const bh8* Wd2f  = (const bh8*)(wsfrag);
  const bh8* Wd2Tf = (const bh8*)(wsfrag + 16384);
  const bh8* We2f  = (const bh8*)(wsfrag + 32768);
  const bh8* We3f  = (const bh8*)(wsfrag + 49152);

  const float x0v = x_ctx[(b*NPT + lane)*2 + 0];
  const float x1v = x_ctx[(b*NPT + lane)*2 + 1];
  const float yv  = y_ctx[b*NPT + lane];
  const float mkv = mask[b*NPT + lane];
  const float inv_msum = 1.0f / fmaxf(wsum64(mkv), 1e-6f);
  const float bd3v = bd3[0];

  // per-lane data for the 4 C-rows this lane holds (points 16w+4*qq+g)
  float x0q[4], x1q[4], yq[4], mkq[4];
  #pragma unroll
  for (int g = 0; g < 4; ++g) {
    const int src = (w << 4) | (qq << 2) | g;
    x0q[g] = __shfl(x0v, src, 64);
    x1q[g] = __shfl(x1v, src, 64);
    yq[g]  = __shfl(yv,  src, 64);
    mkq[g] = __shfl(mkv, src, 64);
  }

  if (tid < 64) zsh[tid] = z0[b*ZD + tid];
  if (tid < 128) {
    bd2sh[tid] = bd2[tid];
    wd3sh[tid] = Wd3[tid];
    wx0sh[tid] = Wd1[64*HD + tid];
    wx1sh[tid] = Wd1[65*HD + tid];
    f1sh[tid]  = be2[tid];
    f2sh[tid]  = be3[tid];
  }
  __syncthreads();

  // ================= encoder =================
  // enc L1: lane=point, wave w computes k-slice kc=w, writes A-frag layout
  #pragma unroll
  for (int quad = 0; quad < 4; ++quad) {
    unsigned int pw[4];
    #pragma unroll
    for (int jj = 0; jj < 8; jj += 2) {
      const int k = 32*w + 8*quad + jj;
      const float sA = be1[k]   + x0v*We1[k]   + x1v*We1[HD+k]   + yv*We1[2*HD+k];
      const float sB = be1[k+1] + x0v*We1[k+1] + x1v*We1[HD+k+1] + yv*We1[2*HD+k+1];
      pw[jj>>1] = packbf(sA*sigf(sA), sB*sigf(sB));
    }
    uint4 v4; v4.x = pw[0]; v4.y = pw[1]; v4.z = pw[2]; v4.w = pw[3];
    ((uint4*)h1f)[(w*4 + (lane>>4))*64 + quad*16 + (lane&15)] = v4;
  }
  __syncthreads();

  // enc L2 (MFMA): H2 = silu(H1 @ We2 + be2) -> tau (A-frag layout, in h1f)
  {
    bh8 af[4];
    #pragma unroll
    for (int kc = 0; kc < 4; ++kc)
      af[kc] = ((const bh8*)h1f)[(kc*4 + w)*64 + lane];
    #pragma unroll 1
    for (int half = 0; half < 2; ++half) {
      const int h4 = half*4;
      fx4 acc[4];
      #pragma unroll
      for (int i = 0; i < 4; ++i) {
        const float bv = f1sh[(h4+i)*16 + rr];
        acc[i] = (fx4){bv, bv, bv, bv};
      }
      #pragma unroll
      for (int i = 0; i < 4; ++i) {
        const int nt = h4 + i;
        const bh8 b0 = We2f[(0*8+nt)*64 + lane];
        const bh8 b1 = We2f[(1*8+nt)*64 + lane];
        const bh8 b2 = We2f[(2*8+nt)*64 + lane];
        const bh8 b3 = We2f[(3*8+nt)*64 + lane];
        acc[i] = __builtin_amdgcn_mfma_f32_16x16x32_bf16(af[0], b0, acc[i], 0,0,0);
        acc[i] = __builtin_amdgcn_mfma_f32_16x16x32_bf16(af[1], b1, acc[i], 0,0,0);
        acc[i] = __builtin_amdgcn_mfma_f32_16x16x32_bf16(af[2], b2, acc[i], 0,0,0);
        acc[i] = __builtin_amdgcn_mfma_f32_16x16x32_bf16(af[3], b3, acc[i], 0,0,0);
      }
      #pragma unroll
      for (int i = 0; i < 4; ++i) {
        const int nt = h4 + i;
        #pragma unroll
        for (int g = 0; g < 4; ++g) {
          const float s2 = acc[i][g];
          const unsigned int tb = bfb(s2 * sigf(s2));
          const unsigned int pb = (unsigned int)__shfl_xor((int)tb, 1, 64);
          if ((rr & 1) == 0) {
            const int unit = ((nt>>1)*4 + w)*64 + (2*(nt&1) + (rr>>3))*16 + 4*qq + g;
            h1f[unit*4 + ((rr&7)>>1)] = tb | (pb << 16);
          }
        }
      }
    }
  }
  wave_sync();

  // enc L3 (MFMA) + masked mean-pool -> rsh
  {
    bh8 tf4[4];
    #pragma unroll
    for (int kc = 0; kc < 4; ++kc)
      tf4[kc] = ((const bh8*)h1f)[(kc*4 + w)*64 + lane];
    #pragma unroll 1
    for (int half = 0; half < 2; ++half) {
      const int h4 = half*4;
      fx4 acc[4];
      #pragma unroll
      for (int i = 0; i < 4; ++i) {
        const float bv = f2sh[(h4+i)*16 + rr];
        acc[i] = (fx4){bv, bv, bv, bv};
      }
      #pragma unroll
      for (int i = 0; i < 4; ++i) {
        const int nt = h4 + i;
        const bh8 b0 = We3f[(0*8+nt)*64 + lane];
        const bh8 b1 = We3f[(1*8+nt)*64 + lane];
        const bh8 b2 = We3f[(2*8+nt)*64 + lane];
        const bh8 b3 = We3f[(3*8+nt)*64 + lane];
        acc[i] = __builtin_amdgcn_mfma_f32_16x16x32_bf16(tf4[0], b0, acc[i], 0,0,0);
        acc[i] = __builtin_amdgcn_mfma_f32_16x16x32_bf16(tf4[1], b1, acc[i], 0,0,0);
        acc[i] = __builtin_amdgcn_mfma_f32_16x16x32_bf16(tf4[2], b2, acc[i], 0,0,0);
        acc[i] = __builtin_amdgcn_mfma_f32_16x16x32_bf16(tf4[3], b3, acc[i], 0,0,0);
      }
      #pragma unroll
      for (int i = 0; i < 4; ++i) {
        float pv = mkq[0]*acc[i][0] + mkq[1]*acc[i][1]
                 + mkq[2]*acc[i][2] + mkq[3]*acc[i][3];
        pv += __shfl_xor(pv, 16, 64);
        pv += __shfl_xor(pv, 32, 64);
        if (lane < 16) dsumP[w*128 + (h4+i)*16 + lane] = pv;
      }
    }
  }
  __syncthreads();
  if (tid < 128)
    rsh[tid] = (dsumP[tid] + dsumP[128+tid] + dsumP[256+tid] + dsumP[384+tid]) * inv_msum;
  __syncthreads();

  // ================= Langevin step loop =================
  for (int st = 0; st < steps; ++st) {
    const float t = (float)st * dt;

    // zW1[k] = bd1[k] + sum_j z[j] Wd1[j,k]
    if (tid < 128) {
      float p0 = bd1[tid], p1 = 0.f, p2 = 0.f, p3 = 0.f;
      #pragma unroll 4
      for (int j = 0; j < 64; j += 4) {
        p0 = fmaf(zsh[j+0], Wd1[(j+0)*HD + tid], p0);
        p1 = fmaf(zsh[j+1], Wd1[(j+1)*HD + tid], p1);
        p2 = fmaf(zsh[j+2], Wd1[(j+2)*HD + tid], p2);
        p3 = fmaf(zsh[j+3], Wd1[(j+3)*HD + tid], p3);
      }
      zw1[tid] = (p0+p1) + (p2+p3);
    }
    __syncthreads();

    // dec L1: h1 = silu(zW1 + x*Wd1x) -> h1f (A-frag layout, kc=w slice)
    #pragma unroll
    for (int quad = 0; quad < 4; ++quad) {
      unsigned int pw[4];
      #pragma unroll
      for (int jj = 0; jj < 8; jj += 2) {
        const int k = 32*w + 8*quad + jj;
        const float sA = zw1[k]   + x0v*wx0sh[k]   + x1v*wx1sh[k];
        const float sB = zw1[k+1] + x0v*wx0sh[k+1] + x1v*wx1sh[k+1];
        pw[jj>>1] = packbf(sA*sigf(sA), sB*sigf(sB));
      }
      uint4 v4; v4.x = pw[0]; v4.y = pw[1]; v4.z = pw[2]; v4.w = pw[3];
      ((uint4*)h1f)[(w*4 + (lane>>4))*64 + quad*16 + (lane&15)] = v4;
    }
    __syncthreads();

    // fwd (MFMA): S2 = H1 @ Wd2 + bd2; emit tau (-> h1f, wave-private slots)
    float ebw[4];
    {
      bh8 af[4];
      #pragma unroll
      for (int kc = 0; kc < 4; ++kc)
        af[kc] = ((const bh8*)h1f)[(kc*4 + w)*64 + lane];
      float da[4] = {0.f, 0.f, 0.f, 0.f};
      #pragma unroll 1
      for (int half = 0; half < 2; ++half) {
        const int h4 = half*4;
        fx4 acc[4];
        #pragma unroll
        for (int i = 0; i < 4; ++i) {
          const float bv = bd2sh[(h4+i)*16 + rr];
          acc[i] = (fx4){bv, bv, bv, bv};
        }
        #pragma unroll
        for (int i = 0; i < 4; ++i) {
          const int nt = h4 + i;
          const bh8 b0 = Wd2f[(0*8+nt)*64 + lane];
          const bh8 b1 = Wd2f[(1*8+nt)*64 + lane];
          const bh8 b2 = Wd2f[(2*8+nt)*64 + lane];
          const bh8 b3 = Wd2f[(3*8+nt)*64 + lane];
          acc[i] = __builtin_amdgcn_mfma_f32_16x16x32_bf16(af[0], b0, acc[i], 0,0,0);
          acc[i] = __builtin_amdgcn_mfma_f32_16x16x32_bf16(af[1], b1, acc[i], 0,0,0);
          acc[i] = __builtin_amdgcn_mfma_f32_16x16x32_bf16(af[2], b2, acc[i], 0,0,0);
          acc[i] = __builtin_amdgcn_mfma_f32_16x16x32_bf16(af[3], b3, acc[i], 0,0,0);
        }
        #pragma unroll
        for (int i = 0; i < 4; ++i) {
          const int nt = h4 + i;
          const float w3 = wd3sh[nt*16 + rr];
          #pragma unroll
          for (int g = 0; g < 4; ++g) {
            const float s2 = acc[i][g];
            const float sg = sigf(s2);
            da[g] = fmaf(s2*sg, w3, da[g]);
            const unsigned int tb = bfb(w3 * (sg * fmaf(s2, 1.0f - sg, 1.0f)));
            const unsigned int pb = (unsigned int)__shfl_xor((int)tb, 1, 64);
            if ((rr & 1) == 0) {
              const int unit = ((nt>>1)*4 + w)*64 + (2*(nt&1) + (rr>>3))*16 + 4*qq + g;
              h1f[unit*4 + ((rr&7)>>1)] = tb | (pb << 16);
            }
          }
        }
      }
      #pragma unroll
      for (int g = 0; g < 4; ++g) {
        float v = da[g];
        v += __shfl_xor(v, 1, 64);
        v += __shfl_xor(v, 2, 64);
        v += __shfl_xor(v, 4, 64);
        v += __shfl_xor(v, 8, 64);
        ebw[g] = t * mkq[g] * (v + bd3v - yq[g]);
      }
    }
    wave_sync();

    // bwd (MFMA): U = TAU @ Wd2^T; dsum[k] = colsum(ebw * silu'(s1) * U)
    {
      bh8 tf4[4];
      #pragma unroll
      for (int kc = 0; kc < 4; ++kc)
        tf4[kc] = ((const bh8*)h1f)[(kc*4 + w)*64 + lane];
      #pragma unroll 1
      for (int half = 0; half < 2; ++half) {
        const int h4 = half*4;
        fx4 u[4];
        #pragma unroll
        for (int i = 0; i < 4; ++i) u[i] = (fx4){0.f, 0.f, 0.f, 0.f};
        #pragma unroll
        for (int i = 0; i < 4; ++i) {
          const int nt = h4 + i;
          const bh8 b0 = Wd2Tf[(0*8+nt)*64 + lane];
          const bh8 b1 = Wd2Tf[(1*8+nt)*64 + lane];
          const bh8 b2 = Wd2Tf[(2*8+nt)*64 + lane];
          const bh8 b3 = Wd2Tf[(3*8+nt)*64 + lane];
          u[i] = __builtin_amdgcn_mfma_f32_16x16x32_bf16(tf4[0], b0, u[i], 0,0,0);
          u[i] = __builtin_amdgcn_mfma_f32_16x16x32_bf16(tf4[1], b1, u[i], 0,0,0);
          u[i] = __builtin_amdgcn_mfma_f32_16x16x32_bf16(tf4[2], b2, u[i], 0,0,0);
          u[i] = __builtin_amdgcn_mfma_f32_16x16x32_bf16(tf4[3], b3, u[i], 0,0,0);
        }
        #pragma unroll
        for (int i = 0; i < 4; ++i) {
          const int nt = h4 + i;
          const float zv = zw1[nt*16 + rr];
          const float wa = wx0sh[nt*16 + rr];
          const float wb = wx1sh[nt*16 + rr];
          float snt = 0.f;
          #pragma unroll
          for (int g = 0; g < 4; ++g) {
            const float s1 = zv + x0q[g]*wa + x1q[g]*wb;
            const float sg = sigf(s1);
            snt += ebw[g] * (sg * fmaf(s1, 1.0f - sg, 1.0f)) * u[i][g];
          }
          snt += __shfl_xor(snt, 16, 64);
          snt += __shfl_xor(snt, 32, 64);
          if (lane < 16) dsumP[w*128 + nt*16 + lane] = snt;
        }
      }
    }
    __syncthreads();

    // dsum combine + drift f1
    if (tid < 128) {
      dsumC[tid] = dsumP[tid] + dsumP[128+tid] + dsumP[256+tid] + dsumP[384+tid];
      float p0 = fmaf(t, Wf1[192*HD + tid], bf1[tid]);
      float p1 = 0.f, p2 = 0.f, p3 = 0.f;
      #pragma unroll 4
      for (int j = 0; j < 64; j += 4) {
        p0 = fmaf(zsh[j+0], Wf1[(j+0)*HD + tid], p0);
        p1 = fmaf(zsh[j+1], Wf1[(j+1)*HD + tid], p1);
        p2 = fmaf(zsh[j+2], Wf1[(j+2)*HD + tid], p2);
        p3 = fmaf(zsh[j+3], Wf1[(j+3)*HD + tid], p3);
      }
      #pragma unroll 4
      for (int j = 0; j < 128; j += 4) {
        p0 = fmaf(rsh[j+0], Wf1[(64+j+0)*HD + tid], p0);
        p1 = fmaf(rsh[j+1], Wf1[(64+j+1)*HD + tid], p1);
        p2 = fmaf(rsh[j+2], Wf1[(64+j+2)*HD + tid], p2);
        p3 = fmaf(rsh[j+3], Wf1[(64+j+3)*HD + tid], p3);
      }
      const float a = (p0+p1) + (p2+p3);
      f1sh[tid] = a * sigf(a);
    }
    __syncthreads();
    if (tid < 128) {
      float p0 = bf2[tid], p1 = 0.f, p2 = 0.f, p3 = 0.f;
      #pragma unroll 4
      for (int j = 0; j < 128; j += 4) {
        p0 = fmaf(f1sh[j+0], Wf2[(j+0)*HD + tid], p0);
        p1 = fmaf(f1sh[j+1], Wf2[(j+1)*HD + tid], p1);
        p2 = fmaf(f1sh[j+2], Wf2[(j+2)*HD + tid], p2);
        p3 = fmaf(f1sh[j+3], Wf2[(j+3)*HD + tid], p3);
      }
      const float a = (p0+p1) + (p2+p3);
      f2sh[tid] = a * sigf(a);
    }
    __syncthreads();
    if (tid < 128) {
      if (tid < 64) {
        float p0 = bf3[tid], p1 = 0.f, p2 = 0.f, p3 = 0.f;
        #pragma unroll 4
        for (int h = 0; h < 128; h += 4) {
          p0 = fmaf(f2sh[h+0], Wf3[(h+0)*ZD + tid], p0);
          p1 = fmaf(f2sh[h+1], Wf3[(h+1)*ZD + tid], p1);
          p2 = fmaf(f2sh[h+2], Wf3[(h+2)*ZD + tid], p2);
          p3 = fmaf(f2sh[h+3], Wf3[(h+3)*ZD + tid], p3);
        }
        bgz[tid] = (p0+p1) + (p2+p3);              // drift output b_j
      } else {
        const int j = tid - 64;
        float p0 = 0.f, p1 = 0.f, p2 = 0.f, p3 = 0.f;
        #pragma unroll 4
        for (int h = 0; h < 128; h += 4) {
          p0 = fmaf(dsumC[h+0], Wd1[j*HD + h+0], p0);
          p1 = fmaf(dsumC[h+1], Wd1[j*HD + h+1], p1);
          p2 = fmaf(dsumC[h+2], Wd1[j*HD + h+2], p2);
          p3 = fmaf(dsumC[h+3], Wd1[j*HD + h+3], p3);
        }
        bgz[64 + j] = (p0+p1) + (p2+p3);           // gz_j (t folded into ebw)
      }
    }
    __syncthreads();
    if (tid < 64) {
      const float zold = zsh[tid];
      float g = zold + bgz[64 + tid];
      g = fminf(fmaxf(g, -100.0f), 100.0f);
      zsh[tid] = zold + (bgz[tid] - g) * dt
               + dco * noises[(size_t)st * (B_TOT * ZD) + b * ZD + tid];
    }
    __syncthreads();
  }

  if (tid < 64) out[b * ZD + tid] = zsh[tid];
}

extern "C" void kernel_launch(void* const* d_in, const int* in_sizes, int n_in,
                              void* d_out, int out_size, void* d_ws, size_t ws_size,
                              hipStream_t stream) {
  const float* x_ctx  = (const float*)d_in[0];
  const float* y_ctx  = (const float*)d_in[1];
  const float* mask   = (const float*)d_in[2];
  const float* z0     = (const float*)d_in[3];
  const float* noises = (const float*)d_in[4];
  const float* We1 = (const float*)d_in[5];  const float* be1 = (const float*)d_in[6];
  const float* We2 = (const float*)d_in[7];  const float* be2 = (const float*)d_in[8];
  const float* We3 = (const float*)d_in[9];  const float* be3 = (const float*)d_in[10];
  const float* Wd1 = (const float*)d_in[11]; const float* bd1 = (const float*)d_in[12];
  const float* Wd2 = (const float*)d_in[13]; const float* bd2 = (const float*)d_in[14];
  const float* Wd3 = (const float*)d_in[15]; const float* bd3 = (const float*)d_in[16];
  const float* Wf1 = (const float*)d_in[17]; const float* bf1 = (const float*)d_in[18];
  const float* Wf2 = (const float*)d_in[19]; const float* bf2 = (const float*)d_in[20];
  const float* Wf3 = (const float*)d_in[21]; const float* bf3 = (const float*)d_in[22];

  const int steps = in_sizes[4] / (B_TOT * ZD);
  const float dt  = 1.0f / (float)steps;
  const float dco = (float)sqrt(2.0 / (double)steps);

  ushort* wsu = (ushort*)d_ws;   // 4 bf16 frag arrays, 128 KB total

  hipLaunchKernelGGL(prep_kernel, dim3(256), dim3(256), 0, stream, Wd2, We2, We3, wsu);
  hipLaunchKernelGGL(metanets_kernel, dim3(B_TOT), dim3(256), 0, stream,
      x_ctx, y_ctx, mask, z0, noises,
      We1, be1, be2, be3,
      Wd1, bd1, bd2, Wd3, bd3,
      Wf1, bf1, Wf2, bf2, Wf3, bf3,
      wsu, (float*)d_out, steps, dt, dco);
}

// Round 3
// 1125.630 us; speedup vs baseline: 1.1776x; 1.0593x over previous
//
#include <hip/hip_runtime.h>
#include <math.h>

// MetaNETS Langevin sampler, MI355X — round 8: wave-role overlap.
// R7 post-mortem: occupancy tracks 512/VGPR at a ~0.40 fill factor in every
// round (LDS never binding); waves sleep at the 7 per-step barriers while
// 128 threads run the serial drift matvecs. This round overlaps the drift
// MLP (f1->f2->f3, independent of the energy-gradient path) with the grad
// path using wave roles, keeping the verified MFMA code identical:
//   S0: waves 0-1: zw1 (own half, wave_sync) + dec L1 (2 kc-slices each)
//       waves 2-3: f1 (the longest chain, 192)   [+ wave 0 prefetches noise]
//   fwd/bwd MFMA: all 4 waves, unchanged.
//   S3: tid<128: dsumC combine  ||  tid>=128: f2
//   S4: wave 0: f3              ||  wave 1: gz
// Barriers 7 -> 5 per step; f1/f2 off the critical path; noise latency hidden.
// tau/h1f aliasing kept from R7 (LDS 24KB). launch_bounds(256,1): keep 80 VGPR.

#define B_TOT 2048
#define NPT   64
#define ZD    64
#define HD    128

typedef short bh8 __attribute__((ext_vector_type(8)));   // 8 x bf16 (4 VGPR)
typedef float fx4 __attribute__((ext_vector_type(4)));   // MFMA C/D

__device__ __forceinline__ float sigf(float x) {
  return __builtin_amdgcn_rcpf(1.0f + __expf(-x));
}
__device__ __forceinline__ unsigned int bfb(float x) {   // fp32 -> bf16 bits (RNE)
  unsigned int u = __float_as_uint(x);
  u += 0x7FFFu + ((u >> 16) & 1u);
  return u >> 16;
}
__device__ __forceinline__ unsigned int packbf(float a, float b) {
  unsigned int ua = __float_as_uint(a), ub = __float_as_uint(b);
  ua += 0x7FFFu + ((ua >> 16) & 1u);
  ub += 0x7FFFu + ((ub >> 16) & 1u);
  return (ua >> 16) | (ub & 0xFFFF0000u);
}
__device__ __forceinline__ float wsum64(float v) {
  #pragma unroll
  for (int d = 1; d < 64; d <<= 1) v += __shfl_xor(v, d, 64);
  return v;
}
__device__ __forceinline__ void wave_sync() {   // intra-wave LDS order + drain
  __builtin_amdgcn_wave_barrier();
  __builtin_amdgcn_s_waitcnt(0xC07F);           // lgkmcnt(0)
  __builtin_amdgcn_wave_barrier();
}

// B-frag arrays (bf16): for W[K=128][N=128] with K = contraction:
//   frag[((kc*8+nt)*64 + L)*8 + j] = W[kc*32 + (L>>4)*8 + j][nt*16 + (L&15)]
// arr0: Wd2 (fwd)   arr1: Wd2^T (bwd)   arr2: We2   arr3: We3
__global__ __launch_bounds__(256)
void prep_kernel(const float* __restrict__ Wd2, const float* __restrict__ We2,
                 const float* __restrict__ We3, ushort* __restrict__ ws) {
  const int id = blockIdx.x * 256 + threadIdx.x;   // 65536 total
  const int arr = id >> 14;
  const int e = id & 16383;
  const int j = e & 7, L = (e >> 3) & 63, nt = (e >> 9) & 7, kc = e >> 12;
  const int kk = kc * 32 + (L >> 4) * 8 + j, nn = nt * 16 + (L & 15);
  float v;
  if      (arr == 0) v = Wd2[kk * HD + nn];
  else if (arr == 1) v = Wd2[nn * HD + kk];    // Wd2^T
  else if (arr == 2) v = We2[kk * HD + nn];
  else               v = We3[kk * HD + nn];
  ws[id] = (ushort)bfb(v);
}

__global__ __launch_bounds__(256, 1)
void metanets_kernel(
    const float* __restrict__ x_ctx, const float* __restrict__ y_ctx,
    const float* __restrict__ mask,  const float* __restrict__ z0,
    const float* __restrict__ noises,
    const float* __restrict__ We1, const float* __restrict__ be1,
    const float* __restrict__ be2, const float* __restrict__ be3,
    const float* __restrict__ Wd1, const float* __restrict__ bd1,
    const float* __restrict__ bd2, const float* __restrict__ Wd3,
    const float* __restrict__ bd3,
    const float* __restrict__ Wf1, const float* __restrict__ bf1,
    const float* __restrict__ Wf2, const float* __restrict__ bf2,
    const float* __restrict__ Wf3, const float* __restrict__ bf3,
    const ushort* __restrict__ wsfrag,
    float* __restrict__ out, int steps, float dt, float dco)
{
  // h1f doubles as the tau buffer (R7 invariant): within fwd/bwd every wave
  // touches only slots == w (mod 4) and A-frags are reg-loaded before the tau
  // scatter overwrites them.
  __shared__ unsigned int h1f[4096];    // A-frag units: [(slot)*64 + lane] x 4 dw
  __shared__ float zsh[64];
  __shared__ float zw1[128];
  __shared__ float rsh[128];
  __shared__ float dsumP[512];
  __shared__ float dsumC[128];
  __shared__ float f1sh[128];           // be2 staging, then drift hidden1
  __shared__ float f2sh[128];           // be3 staging, then drift hidden2
  __shared__ float bgz[128];
  __shared__ float bd2sh[128], wd3sh[128], wx0sh[128], wx1sh[128];

  const int tid = threadIdx.x;
  const int lane = tid & 63;                                  // context point
  const int w = __builtin_amdgcn_readfirstlane(tid >> 6);     // wave = m-tile
  const int b = blockIdx.x;
  const int rr = lane & 15, qq = lane >> 4;

  const bh8* Wd2f  = (const bh8*)(wsfrag);
  const bh8* Wd2Tf = (const bh8*)(wsfrag + 16384);
  const bh8* We2f  = (const bh8*)(wsfrag + 32768);
  const bh8* We3f  = (const bh8*)(wsfrag + 49152);

  const float x0v = x_ctx[(b*NPT + lane)*2 + 0];
  const float x1v = x_ctx[(b*NPT + lane)*2 + 1];
  const float yv  = y_ctx[b*NPT + lane];
  const float mkv = mask[b*NPT + lane];
  const float inv_msum = 1.0f / fmaxf(wsum64(mkv), 1e-6f);
  const float bd3v = bd3[0];

  // per-lane data for the 4 C-rows this lane holds (points 16w+4*qq+g)
  float x0q[4], x1q[4], yq[4], mkq[4];
  #pragma unroll
  for (int g = 0; g < 4; ++g) {
    const int src = (w << 4) | (qq << 2) | g;
    x0q[g] = __shfl(x0v, src, 64);
    x1q[g] = __shfl(x1v, src, 64);
    yq[g]  = __shfl(yv,  src, 64);
    mkq[g] = __shfl(mkv, src, 64);
  }

  if (tid < 64) zsh[tid] = z0[b*ZD + tid];
  if (tid < 128) {
    bd2sh[tid] = bd2[tid];
    wd3sh[tid] = Wd3[tid];
    wx0sh[tid] = Wd1[64*HD + tid];
    wx1sh[tid] = Wd1[65*HD + tid];
    f1sh[tid]  = be2[tid];
    f2sh[tid]  = be3[tid];
  }
  __syncthreads();

  // ================= encoder =================
  // enc L1: lane=point, wave w computes k-slice kc=w, writes A-frag layout
  #pragma unroll
  for (int quad = 0; quad < 4; ++quad) {
    unsigned int pw[4];
    #pragma unroll
    for (int jj = 0; jj < 8; jj += 2) {
      const int k = 32*w + 8*quad + jj;
      const float sA = be1[k]   + x0v*We1[k]   + x1v*We1[HD+k]   + yv*We1[2*HD+k];
      const float sB = be1[k+1] + x0v*We1[k+1] + x1v*We1[HD+k+1] + yv*We1[2*HD+k+1];
      pw[jj>>1] = packbf(sA*sigf(sA), sB*sigf(sB));
    }
    uint4 v4; v4.x = pw[0]; v4.y = pw[1]; v4.z = pw[2]; v4.w = pw[3];
    ((uint4*)h1f)[(w*4 + (lane>>4))*64 + quad*16 + (lane&15)] = v4;
  }
  __syncthreads();

  // enc L2 (MFMA): H2 = silu(H1 @ We2 + be2) -> tau (A-frag layout, in h1f)
  {
    bh8 af[4];
    #pragma unroll
    for (int kc = 0; kc < 4; ++kc)
      af[kc] = ((const bh8*)h1f)[(kc*4 + w)*64 + lane];
    #pragma unroll 1
    for (int half = 0; half < 2; ++half) {
      const int h4 = half*4;
      fx4 acc[4];
      #pragma unroll
      for (int i = 0; i < 4; ++i) {
        const float bv = f1sh[(h4+i)*16 + rr];
        acc[i] = (fx4){bv, bv, bv, bv};
      }
      #pragma unroll
      for (int i = 0; i < 4; ++i) {
        const int nt = h4 + i;
        const bh8 b0 = We2f[(0*8+nt)*64 + lane];
        const bh8 b1 = We2f[(1*8+nt)*64 + lane];
        const bh8 b2 = We2f[(2*8+nt)*64 + lane];
        const bh8 b3 = We2f[(3*8+nt)*64 + lane];
        acc[i] = __builtin_amdgcn_mfma_f32_16x16x32_bf16(af[0], b0, acc[i], 0,0,0);
        acc[i] = __builtin_amdgcn_mfma_f32_16x16x32_bf16(af[1], b1, acc[i], 0,0,0);
        acc[i] = __builtin_amdgcn_mfma_f32_16x16x32_bf16(af[2], b2, acc[i], 0,0,0);
        acc[i] = __builtin_amdgcn_mfma_f32_16x16x32_bf16(af[3], b3, acc[i], 0,0,0);
      }
      #pragma unroll
      for (int i = 0; i < 4; ++i) {
        const int nt = h4 + i;
        #pragma unroll
        for (int g = 0; g < 4; ++g) {
          const float s2 = acc[i][g];
          const unsigned int tb = bfb(s2 * sigf(s2));
          const unsigned int pb = (unsigned int)__shfl_xor((int)tb, 1, 64);
          if ((rr & 1) == 0) {
            const int unit = ((nt>>1)*4 + w)*64 + (2*(nt&1) + (rr>>3))*16 + 4*qq + g;
            h1f[unit*4 + ((rr&7)>>1)] = tb | (pb << 16);
          }
        }
      }
    }
  }
  wave_sync();

  // enc L3 (MFMA) + masked mean-pool -> rsh
  {
    bh8 tf4[4];
    #pragma unroll
    for (int kc = 0; kc < 4; ++kc)
      tf4[kc] = ((const bh8*)h1f)[(kc*4 + w)*64 + lane];
    #pragma unroll 1
    for (int half = 0; half < 2; ++half) {
      const int h4 = half*4;
      fx4 acc[4];
      #pragma unroll
      for (int i = 0; i < 4; ++i) {
        const float bv = f2sh[(h4+i)*16 + rr];
        acc[i] = (fx4){bv, bv, bv, bv};
      }
      #pragma unroll
      for (int i = 0; i < 4; ++i) {
        const int nt = h4 + i;
        const bh8 b0 = We3f[(0*8+nt)*64 + lane];
        const bh8 b1 = We3f[(1*8+nt)*64 + lane];
        const bh8 b2 = We3f[(2*8+nt)*64 + lane];
        const bh8 b3 = We3f[(3*8+nt)*64 + lane];
        acc[i] = __builtin_amdgcn_mfma_f32_16x16x32_bf16(tf4[0], b0, acc[i], 0,0,0);
        acc[i] = __builtin_amdgcn_mfma_f32_16x16x32_bf16(tf4[1], b1, acc[i], 0,0,0);
        acc[i] = __builtin_amdgcn_mfma_f32_16x16x32_bf16(tf4[2], b2, acc[i], 0,0,0);
        acc[i] = __builtin_amdgcn_mfma_f32_16x16x32_bf16(tf4[3], b3, acc[i], 0,0,0);
      }
      #pragma unroll
      for (int i = 0; i < 4; ++i) {
        float pv = mkq[0]*acc[i][0] + mkq[1]*acc[i][1]
                 + mkq[2]*acc[i][2] + mkq[3]*acc[i][3];
        pv += __shfl_xor(pv, 16, 64);
        pv += __shfl_xor(pv, 32, 64);
        if (lane < 16) dsumP[w*128 + (h4+i)*16 + lane] = pv;
      }
    }
  }
  __syncthreads();
  if (tid < 128)
    rsh[tid] = (dsumP[tid] + dsumP[128+tid] + dsumP[256+tid] + dsumP[384+tid]) * inv_msum;
  __syncthreads();

  // ================= Langevin step loop =================
  for (int st = 0; st < steps; ++st) {
    const float t = (float)st * dt;

    // noise prefetch (wave 0): issued here, consumed at the z-update — the
    // HBM/L2 latency hides under S0..S4.
    float noise_v = 0.f;
    if (tid < 64)
      noise_v = noises[(size_t)st * (B_TOT * ZD) + b * ZD + tid];

    // ---- S0: waves 0-1: zw1 + dec L1 (2 kc-slices each) || waves 2-3: f1
    if (w < 2) {
      // zw1[tid] = bd1[tid] + sum_j z[j] Wd1[j,tid]   (tid in [0,128))
      {
        float p0 = bd1[tid], p1 = 0.f, p2 = 0.f, p3 = 0.f;
        #pragma unroll 4
        for (int j = 0; j < 64; j += 4) {
          p0 = fmaf(zsh[j+0], Wd1[(j+0)*HD + tid], p0);
          p1 = fmaf(zsh[j+1], Wd1[(j+1)*HD + tid], p1);
          p2 = fmaf(zsh[j+2], Wd1[(j+2)*HD + tid], p2);
          p3 = fmaf(zsh[j+3], Wd1[(j+3)*HD + tid], p3);
        }
        zw1[tid] = (p0+p1) + (p2+p3);
      }
      wave_sync();   // wave w' wrote zw1[64w'..64w'+64); its dec L1 reads only those
      // dec L1: h1 = silu(zW1 + x*Wd1x) -> h1f, kc slices {2w, 2w+1}
      #pragma unroll
      for (int kq = 0; kq < 2; ++kq) {
        const int kcs = 2*w + kq;
        #pragma unroll
        for (int quad = 0; quad < 4; ++quad) {
          unsigned int pw[4];
          #pragma unroll
          for (int jj = 0; jj < 8; jj += 2) {
            const int k = 32*kcs + 8*quad + jj;
            const float sA = zw1[k]   + x0v*wx0sh[k]   + x1v*wx1sh[k];
            const float sB = zw1[k+1] + x0v*wx0sh[k+1] + x1v*wx1sh[k+1];
            pw[jj>>1] = packbf(sA*sigf(sA), sB*sigf(sB));
          }
          uint4 v4; v4.x = pw[0]; v4.y = pw[1]; v4.z = pw[2]; v4.w = pw[3];
          ((uint4*)h1f)[(kcs*4 + (lane>>4))*64 + quad*16 + (lane&15)] = v4;
        }
      }
    } else {
      // f1[o] = silu(bf1 + t*Wf1_t + z@Wf1_z + r@Wf1_r)   (o in [0,128))
      const int o = tid - 128;
      float p0 = fmaf(t, Wf1[192*HD + o], bf1[o]);
      float p1 = 0.f, p2 = 0.f, p3 = 0.f;
      #pragma unroll 4
      for (int j = 0; j < 64; j += 4) {
        p0 = fmaf(zsh[j+0], Wf1[(j+0)*HD + o], p0);
        p1 = fmaf(zsh[j+1], Wf1[(j+1)*HD + o], p1);
        p2 = fmaf(zsh[j+2], Wf1[(j+2)*HD + o], p2);
        p3 = fmaf(zsh[j+3], Wf1[(j+3)*HD + o], p3);
      }
      #pragma unroll 4
      for (int j = 0; j < 128; j += 4) {
        p0 = fmaf(rsh[j+0], Wf1[(64+j+0)*HD + o], p0);
        p1 = fmaf(rsh[j+1], Wf1[(64+j+1)*HD + o], p1);
        p2 = fmaf(rsh[j+2], Wf1[(64+j+2)*HD + o], p2);
        p3 = fmaf(rsh[j+3], Wf1[(64+j+3)*HD + o], p3);
      }
      const float a = (p0+p1) + (p2+p3);
      f1sh[o] = a * sigf(a);
    }
    __syncthreads();   // B1: h1f (all kc slices) + f1sh ready

    // fwd (MFMA): S2 = H1 @ Wd2 + bd2; emit tau (-> h1f, wave-private slots)
    float ebw[4];
    {
      bh8 af[4];
      #pragma unroll
      for (int kc = 0; kc < 4; ++kc)
        af[kc] = ((const bh8*)h1f)[(kc*4 + w)*64 + lane];
      float da[4] = {0.f, 0.f, 0.f, 0.f};
      #pragma unroll 1
      for (int half = 0; half < 2; ++half) {
        const int h4 = half*4;
        fx4 acc[4];
        #pragma unroll
        for (int i = 0; i < 4; ++i) {
          const float bv = bd2sh[(h4+i)*16 + rr];
          acc[i] = (fx4){bv, bv, bv, bv};
        }
        #pragma unroll
        for (int i = 0; i < 4; ++i) {
          const int nt = h4 + i;
          const bh8 b0 = Wd2f[(0*8+nt)*64 + lane];
          const bh8 b1 = Wd2f[(1*8+nt)*64 + lane];
          const bh8 b2 = Wd2f[(2*8+nt)*64 + lane];
          const bh8 b3 = Wd2f[(3*8+nt)*64 + lane];
          acc[i] = __builtin_amdgcn_mfma_f32_16x16x32_bf16(af[0], b0, acc[i], 0,0,0);
          acc[i] = __builtin_amdgcn_mfma_f32_16x16x32_bf16(af[1], b1, acc[i], 0,0,0);
          acc[i] = __builtin_amdgcn_mfma_f32_16x16x32_bf16(af[2], b2, acc[i], 0,0,0);
          acc[i] = __builtin_amdgcn_mfma_f32_16x16x32_bf16(af[3], b3, acc[i], 0,0,0);
        }
        #pragma unroll
        for (int i = 0; i < 4; ++i) {
          const int nt = h4 + i;
          const float w3 = wd3sh[nt*16 + rr];
          #pragma unroll
          for (int g = 0; g < 4; ++g) {
            const float s2 = acc[i][g];
            const float sg = sigf(s2);
            da[g] = fmaf(s2*sg, w3, da[g]);
            const unsigned int tb = bfb(w3 * (sg * fmaf(s2, 1.0f - sg, 1.0f)));
            const unsigned int pb = (unsigned int)__shfl_xor((int)tb, 1, 64);
            if ((rr & 1) == 0) {
              const int unit = ((nt>>1)*4 + w)*64 + (2*(nt&1) + (rr>>3))*16 + 4*qq + g;
              h1f[unit*4 + ((rr&7)>>1)] = tb | (pb << 16);
            }
          }
        }
      }
      #pragma unroll
      for (int g = 0; g < 4; ++g) {
        float v = da[g];
        v += __shfl_xor(v, 1, 64);
        v += __shfl_xor(v, 2, 64);
        v += __shfl_xor(v, 4, 64);
        v += __shfl_xor(v, 8, 64);
        ebw[g] = t * mkq[g] * (v + bd3v - yq[g]);
      }
    }
    wave_sync();

    // bwd (MFMA): U = TAU @ Wd2^T; dsum[k] = colsum(ebw * silu'(s1) * U)
    {
      bh8 tf4[4];
      #pragma unroll
      for (int kc = 0; kc < 4; ++kc)
        tf4[kc] = ((const bh8*)h1f)[(kc*4 + w)*64 + lane];
      #pragma unroll 1
      for (int half = 0; half < 2; ++half) {
        const int h4 = half*4;
        fx4 u[4];
        #pragma unroll
        for (int i = 0; i < 4; ++i) u[i] = (fx4){0.f, 0.f, 0.f, 0.f};
        #pragma unroll
        for (int i = 0; i < 4; ++i) {
          const int nt = h4 + i;
          const bh8 b0 = Wd2Tf[(0*8+nt)*64 + lane];
          const bh8 b1 = Wd2Tf[(1*8+nt)*64 + lane];
          const bh8 b2 = Wd2Tf[(2*8+nt)*64 + lane];
          const bh8 b3 = Wd2Tf[(3*8+nt)*64 + lane];
          u[i] = __builtin_amdgcn_mfma_f32_16x16x32_bf16(tf4[0], b0, u[i], 0,0,0);
          u[i] = __builtin_amdgcn_mfma_f32_16x16x32_bf16(tf4[1], b1, u[i], 0,0,0);
          u[i] = __builtin_amdgcn_mfma_f32_16x16x32_bf16(tf4[2], b2, u[i], 0,0,0);
          u[i] = __builtin_amdgcn_mfma_f32_16x16x32_bf16(tf4[3], b3, u[i], 0,0,0);
        }
        #pragma unroll
        for (int i = 0; i < 4; ++i) {
          const int nt = h4 + i;
          const float zv = zw1[nt*16 + rr];
          const float wa = wx0sh[nt*16 + rr];
          const float wb = wx1sh[nt*16 + rr];
          float snt = 0.f;
          #pragma unroll
          for (int g = 0; g < 4; ++g) {
            const float s1 = zv + x0q[g]*wa + x1q[g]*wb;
            const float sg = sigf(s1);
            snt += ebw[g] * (sg * fmaf(s1, 1.0f - sg, 1.0f)) * u[i][g];
          }
          snt += __shfl_xor(snt, 16, 64);
          snt += __shfl_xor(snt, 32, 64);
          if (lane < 16) dsumP[w*128 + nt*16 + lane] = snt;
        }
      }
    }
    __syncthreads();   // B3: dsumP ready

    // ---- S3: tid<128: dsumC combine  ||  tid>=128: f2
    if (tid < 128) {
      dsumC[tid] = dsumP[tid] + dsumP[128+tid] + dsumP[256+tid] + dsumP[384+tid];
    } else {
      const int o = tid - 128;
      float p0 = bf2[o], p1 = 0.f, p2 = 0.f, p3 = 0.f;
      #pragma unroll 4
      for (int j = 0; j < 128; j += 4) {
        p0 = fmaf(f1sh[j+0], Wf2[(j+0)*HD + o], p0);
        p1 = fmaf(f1sh[j+1], Wf2[(j+1)*HD + o], p1);
        p2 = fmaf(f1sh[j+2], Wf2[(j+2)*HD + o], p2);
        p3 = fmaf(f1sh[j+3], Wf2[(j+3)*HD + o], p3);
      }
      const float a = (p0+p1) + (p2+p3);
      f2sh[o] = a * sigf(a);
    }
    __syncthreads();   // B4: dsumC + f2sh ready

    // ---- S4: wave 0: f3 (drift out)  ||  wave 1: gz (dec-grad)
    if (tid < 64) {
      float p0 = bf3[tid], p1 = 0.f, p2 = 0.f, p3 = 0.f;
      #pragma unroll 4
      for (int h = 0; h < 128; h += 4) {
        p0 = fmaf(f2sh[h+0], Wf3[(h+0)*ZD + tid], p0);
        p1 = fmaf(f2sh[h+1], Wf3[(h+1)*ZD + tid], p1);
        p2 = fmaf(f2sh[h+2], Wf3[(h+2)*ZD + tid], p2);
        p3 = fmaf(f2sh[h+3], Wf3[(h+3)*ZD + tid], p3);
      }
      bgz[tid] = (p0+p1) + (p2+p3);              // drift output b_j
    } else if (tid < 128) {
      const int j = tid - 64;
      float p0 = 0.f, p1 = 0.f, p2 = 0.f, p3 = 0.f;
      #pragma unroll 4
      for (int h = 0; h < 128; h += 4) {
        p0 = fmaf(dsumC[h+0], Wd1[j*HD + h+0], p0);
        p1 = fmaf(dsumC[h+1], Wd1[j*HD + h+1], p1);
        p2 = fmaf(dsumC[h+2], Wd1[j*HD + h+2], p2);
        p3 = fmaf(dsumC[h+3], Wd1[j*HD + h+3], p3);
      }
      bgz[64 + j] = (p0+p1) + (p2+p3);           // gz_j (t folded into ebw)
    }
    __syncthreads();   // B5: bgz ready

    if (tid < 64) {
      const float zold = zsh[tid];
      float g = zold + bgz[64 + tid];
      g = fminf(fmaxf(g, -100.0f), 100.0f);
      zsh[tid] = zold + (bgz[tid] - g) * dt + dco * noise_v;
    }
    __syncthreads();   // B6: zsh ready for next step
  }

  if (tid < 64) out[b * ZD + tid] = zsh[tid];
}

extern "C" void kernel_launch(void* const* d_in, const int* in_sizes, int n_in,
                              void* d_out, int out_size, void* d_ws, size_t ws_size,
                              hipStream_t stream) {
  const float* x_ctx  = (const float*)d_in[0];
  const float* y_ctx  = (const float*)d_in[1];
  const float* mask   = (const float*)d_in[2];
  const float* z0     = (const float*)d_in[3];
  const float* noises = (const float*)d_in[4];
  const float* We1 = (const float*)d_in[5];  const float* be1 = (const float*)d_in[6];
  const float* We2 = (const float*)d_in[7];  const float* be2 = (const float*)d_in[8];
  const float* We3 = (const float*)d_in[9];  const float* be3 = (const float*)d_in[10];
  const float* Wd1 = (const float*)d_in[11]; const float* bd1 = (const float*)d_in[12];
  const float* Wd2 = (const float*)d_in[13]; const float* bd2 = (const float*)d_in[14];
  const float* Wd3 = (const float*)d_in[15]; const float* bd3 = (const float*)d_in[16];
  const float* Wf1 = (const float*)d_in[17]; const float* bf1 = (const float*)d_in[18];
  const float* Wf2 = (const float*)d_in[19]; const float* bf2 = (const float*)d_in[20];
  const float* Wf3 = (const float*)d_in[21]; const float* bf3 = (const float*)d_in[22];

  const int steps = in_sizes[4] / (B_TOT * ZD);
  const float dt  = 1.0f / (float)steps;
  const float dco = (float)sqrt(2.0 / (double)steps);

  ushort* wsu = (ushort*)d_ws;   // 4 bf16 frag arrays, 128 KB total

  hipLaunchKernelGGL(prep_kernel, dim3(256), dim3(256), 0, stream, Wd2, We2, We3, wsu);
  hipLaunchKernelGGL(metanets_kernel, dim3(B_TOT), dim3(256), 0, stream,
      x_ctx, y_ctx, mask, z0, noises,
      We1, be1, be2, be3,
      Wd1, bd1, bd2, Wd3, bd3,
      Wf1, bf1, Wf2, bf2, Wf3, bf3,
      wsu, (float*)d_out, steps, dt, dco);
}

// Round 4
// 1116.898 us; speedup vs baseline: 1.1868x; 1.0078x over previous
//
#include <hip/hip_runtime.h>
#include <math.h>

// MetaNETS Langevin sampler, MI355X — round 9: hoist step-invariant drift work
// + split the tail chains.
// R8 post-mortem: 80 and 112 VGPR are the SAME occupancy bin (waves/SIMD steps
// at 64/128/256 — m69), so residency is pinned at 4 waves/SIMD regardless of
// LDS; gains must come from the serial per-step chain. Changes vs R8:
//  (1) rW1 precompute: f1's r-contraction (128 of 193 MACs + loads) is
//      step-invariant -> hoisted before the loop (rw1sh = bf1 + r@Wf1_r);
//      the t-row Wf1[192] is staged once (wt1sh). f1 chain 193 -> 65.
//  (2) tail S4: f3 and gz each 2-way k-split across all 256 threads
//      (64-chains; partials in dead LDS: dsumP[0:128] gz, bgz[0:128] f3;
//      combined in the z-update). Register-neutral split.
// Everything else identical to R8 (wave-role overlap, tau/h1f aliasing,
// 4-wave MFMA fwd/bwd). launch_bounds(256,1): keep ~80 VGPR.

#define B_TOT 2048
#define NPT   64
#define ZD    64
#define HD    128

typedef short bh8 __attribute__((ext_vector_type(8)));   // 8 x bf16 (4 VGPR)
typedef float fx4 __attribute__((ext_vector_type(4)));   // MFMA C/D

__device__ __forceinline__ float sigf(float x) {
  return __builtin_amdgcn_rcpf(1.0f + __expf(-x));
}
__device__ __forceinline__ unsigned int bfb(float x) {   // fp32 -> bf16 bits (RNE)
  unsigned int u = __float_as_uint(x);
  u += 0x7FFFu + ((u >> 16) & 1u);
  return u >> 16;
}
__device__ __forceinline__ unsigned int packbf(float a, float b) {
  unsigned int ua = __float_as_uint(a), ub = __float_as_uint(b);
  ua += 0x7FFFu + ((ua >> 16) & 1u);
  ub += 0x7FFFu + ((ub >> 16) & 1u);
  return (ua >> 16) | (ub & 0xFFFF0000u);
}
__device__ __forceinline__ float wsum64(float v) {
  #pragma unroll
  for (int d = 1; d < 64; d <<= 1) v += __shfl_xor(v, d, 64);
  return v;
}
__device__ __forceinline__ void wave_sync() {   // intra-wave LDS order + drain
  __builtin_amdgcn_wave_barrier();
  __builtin_amdgcn_s_waitcnt(0xC07F);           // lgkmcnt(0)
  __builtin_amdgcn_wave_barrier();
}

// B-frag arrays (bf16): for W[K=128][N=128] with K = contraction:
//   frag[((kc*8+nt)*64 + L)*8 + j] = W[kc*32 + (L>>4)*8 + j][nt*16 + (L&15)]
// arr0: Wd2 (fwd)   arr1: Wd2^T (bwd)   arr2: We2   arr3: We3
__global__ __launch_bounds__(256)
void prep_kernel(const float* __restrict__ Wd2, const float* __restrict__ We2,
                 const float* __restrict__ We3, ushort* __restrict__ ws) {
  const int id = blockIdx.x * 256 + threadIdx.x;   // 65536 total
  const int arr = id >> 14;
  const int e = id & 16383;
  const int j = e & 7, L = (e >> 3) & 63, nt = (e >> 9) & 7, kc = e >> 12;
  const int kk = kc * 32 + (L >> 4) * 8 + j, nn = nt * 16 + (L & 15);
  float v;
  if      (arr == 0) v = Wd2[kk * HD + nn];
  else if (arr == 1) v = Wd2[nn * HD + kk];    // Wd2^T
  else if (arr == 2) v = We2[kk * HD + nn];
  else               v = We3[kk * HD + nn];
  ws[id] = (ushort)bfb(v);
}

__global__ __launch_bounds__(256, 1)
void metanets_kernel(
    const float* __restrict__ x_ctx, const float* __restrict__ y_ctx,
    const float* __restrict__ mask,  const float* __restrict__ z0,
    const float* __restrict__ noises,
    const float* __restrict__ We1, const float* __restrict__ be1,
    const float* __restrict__ be2, const float* __restrict__ be3,
    const float* __restrict__ Wd1, const float* __restrict__ bd1,
    const float* __restrict__ bd2, const float* __restrict__ Wd3,
    const float* __restrict__ bd3,
    const float* __restrict__ Wf1, const float* __restrict__ bf1,
    const float* __restrict__ Wf2, const float* __restrict__ bf2,
    const float* __restrict__ Wf3, const float* __restrict__ bf3,
    const ushort* __restrict__ wsfrag,
    float* __restrict__ out, int steps, float dt, float dco)
{
  // h1f doubles as the tau buffer (R7 invariant): within fwd/bwd every wave
  // touches only slots == w (mod 4) and A-frags are reg-loaded before the tau
  // scatter overwrites them.
  __shared__ unsigned int h1f[4096];    // A-frag units: [(slot)*64 + lane] x 4 dw
  __shared__ float zsh[64];
  __shared__ float zw1[128];
  __shared__ float rsh[128];
  __shared__ float dsumP[512];
  __shared__ float dsumC[128];
  __shared__ float f1sh[128];           // be2 staging, then drift hidden1
  __shared__ float f2sh[128];           // be3 staging, then drift hidden2
  __shared__ float bgz[128];            // R9: f3 k-split partials (2x64)
  __shared__ float rw1sh[128];          // R9: bf1 + r @ Wf1_r (step-invariant)
  __shared__ float wt1sh[128];          // R9: Wf1 t-row staged
  __shared__ float bd2sh[128], wd3sh[128], wx0sh[128], wx1sh[128];

  const int tid = threadIdx.x;
  const int lane = tid & 63;                                  // context point
  const int w = __builtin_amdgcn_readfirstlane(tid >> 6);     // wave = m-tile
  const int b = blockIdx.x;
  const int rr = lane & 15, qq = lane >> 4;

  const bh8* Wd2f  = (const bh8*)(wsfrag);
  const bh8* Wd2Tf = (const bh8*)(wsfrag + 16384);
  const bh8* We2f  = (const bh8*)(wsfrag + 32768);
  const bh8* We3f  = (const bh8*)(wsfrag + 49152);

  const float x0v = x_ctx[(b*NPT + lane)*2 + 0];
  const float x1v = x_ctx[(b*NPT + lane)*2 + 1];
  const float yv  = y_ctx[b*NPT + lane];
  const float mkv = mask[b*NPT + lane];
  const float inv_msum = 1.0f / fmaxf(wsum64(mkv), 1e-6f);
  const float bd3v = bd3[0];

  // per-lane data for the 4 C-rows this lane holds (points 16w+4*qq+g)
  float x0q[4], x1q[4], yq[4], mkq[4];
  #pragma unroll
  for (int g = 0; g < 4; ++g) {
    const int src = (w << 4) | (qq << 2) | g;
    x0q[g] = __shfl(x0v, src, 64);
    x1q[g] = __shfl(x1v, src, 64);
    yq[g]  = __shfl(yv,  src, 64);
    mkq[g] = __shfl(mkv, src, 64);
  }

  if (tid < 64) zsh[tid] = z0[b*ZD + tid];
  if (tid < 128) {
    bd2sh[tid] = bd2[tid];
    wd3sh[tid] = Wd3[tid];
    wx0sh[tid] = Wd1[64*HD + tid];
    wx1sh[tid] = Wd1[65*HD + tid];
    f1sh[tid]  = be2[tid];
    f2sh[tid]  = be3[tid];
    wt1sh[tid] = Wf1[192*HD + tid];
  }
  __syncthreads();

  // ================= encoder =================
  // enc L1: lane=point, wave w computes k-slice kc=w, writes A-frag layout
  #pragma unroll
  for (int quad = 0; quad < 4; ++quad) {
    unsigned int pw[4];
    #pragma unroll
    for (int jj = 0; jj < 8; jj += 2) {
      const int k = 32*w + 8*quad + jj;
      const float sA = be1[k]   + x0v*We1[k]   + x1v*We1[HD+k]   + yv*We1[2*HD+k];
      const float sB = be1[k+1] + x0v*We1[k+1] + x1v*We1[HD+k+1] + yv*We1[2*HD+k+1];
      pw[jj>>1] = packbf(sA*sigf(sA), sB*sigf(sB));
    }
    uint4 v4; v4.x = pw[0]; v4.y = pw[1]; v4.z = pw[2]; v4.w = pw[3];
    ((uint4*)h1f)[(w*4 + (lane>>4))*64 + quad*16 + (lane&15)] = v4;
  }
  __syncthreads();

  // enc L2 (MFMA): H2 = silu(H1 @ We2 + be2) -> tau (A-frag layout, in h1f)
  {
    bh8 af[4];
    #pragma unroll
    for (int kc = 0; kc < 4; ++kc)
      af[kc] = ((const bh8*)h1f)[(kc*4 + w)*64 + lane];
    #pragma unroll 1
    for (int half = 0; half < 2; ++half) {
      const int h4 = half*4;
      fx4 acc[4];
      #pragma unroll
      for (int i = 0; i < 4; ++i) {
        const float bv = f1sh[(h4+i)*16 + rr];
        acc[i] = (fx4){bv, bv, bv, bv};
      }
      #pragma unroll
      for (int i = 0; i < 4; ++i) {
        const int nt = h4 + i;
        const bh8 b0 = We2f[(0*8+nt)*64 + lane];
        const bh8 b1 = We2f[(1*8+nt)*64 + lane];
        const bh8 b2 = We2f[(2*8+nt)*64 + lane];
        const bh8 b3 = We2f[(3*8+nt)*64 + lane];
        acc[i] = __builtin_amdgcn_mfma_f32_16x16x32_bf16(af[0], b0, acc[i], 0,0,0);
        acc[i] = __builtin_amdgcn_mfma_f32_16x16x32_bf16(af[1], b1, acc[i], 0,0,0);
        acc[i] = __builtin_amdgcn_mfma_f32_16x16x32_bf16(af[2], b2, acc[i], 0,0,0);
        acc[i] = __builtin_amdgcn_mfma_f32_16x16x32_bf16(af[3], b3, acc[i], 0,0,0);
      }
      #pragma unroll
      for (int i = 0; i < 4; ++i) {
        const int nt = h4 + i;
        #pragma unroll
        for (int g = 0; g < 4; ++g) {
          const float s2 = acc[i][g];
          const unsigned int tb = bfb(s2 * sigf(s2));
          const unsigned int pb = (unsigned int)__shfl_xor((int)tb, 1, 64);
          if ((rr & 1) == 0) {
            const int unit = ((nt>>1)*4 + w)*64 + (2*(nt&1) + (rr>>3))*16 + 4*qq + g;
            h1f[unit*4 + ((rr&7)>>1)] = tb | (pb << 16);
          }
        }
      }
    }
  }
  wave_sync();

  // enc L3 (MFMA) + masked mean-pool -> rsh
  {
    bh8 tf4[4];
    #pragma unroll
    for (int kc = 0; kc < 4; ++kc)
      tf4[kc] = ((const bh8*)h1f)[(kc*4 + w)*64 + lane];
    #pragma unroll 1
    for (int half = 0; half < 2; ++half) {
      const int h4 = half*4;
      fx4 acc[4];
      #pragma unroll
      for (int i = 0; i < 4; ++i) {
        const float bv = f2sh[(h4+i)*16 + rr];
        acc[i] = (fx4){bv, bv, bv, bv};
      }
      #pragma unroll
      for (int i = 0; i < 4; ++i) {
        const int nt = h4 + i;
        const bh8 b0 = We3f[(0*8+nt)*64 + lane];
        const bh8 b1 = We3f[(1*8+nt)*64 + lane];
        const bh8 b2 = We3f[(2*8+nt)*64 + lane];
        const bh8 b3 = We3f[(3*8+nt)*64 + lane];
        acc[i] = __builtin_amdgcn_mfma_f32_16x16x32_bf16(tf4[0], b0, acc[i], 0,0,0);
        acc[i] = __builtin_amdgcn_mfma_f32_16x16x32_bf16(tf4[1], b1, acc[i], 0,0,0);
        acc[i] = __builtin_amdgcn_mfma_f32_16x16x32_bf16(tf4[2], b2, acc[i], 0,0,0);
        acc[i] = __builtin_amdgcn_mfma_f32_16x16x32_bf16(tf4[3], b3, acc[i], 0,0,0);
      }
      #pragma unroll
      for (int i = 0; i < 4; ++i) {
        float pv = mkq[0]*acc[i][0] + mkq[1]*acc[i][1]
                 + mkq[2]*acc[i][2] + mkq[3]*acc[i][3];
        pv += __shfl_xor(pv, 16, 64);
        pv += __shfl_xor(pv, 32, 64);
        if (lane < 16) dsumP[w*128 + (h4+i)*16 + lane] = pv;
      }
    }
  }
  __syncthreads();
  if (tid < 128)
    rsh[tid] = (dsumP[tid] + dsumP[128+tid] + dsumP[256+tid] + dsumP[384+tid]) * inv_msum;
  __syncthreads();

  // rW1 precompute (once): rw1sh = bf1 + r @ Wf1_r  (step-invariant part of f1)
  if (tid < 128) {
    float p0 = bf1[tid], p1 = 0.f, p2 = 0.f, p3 = 0.f;
    #pragma unroll 4
    for (int j = 0; j < 128; j += 4) {
      p0 = fmaf(rsh[j+0], Wf1[(64+j+0)*HD + tid], p0);
      p1 = fmaf(rsh[j+1], Wf1[(64+j+1)*HD + tid], p1);
      p2 = fmaf(rsh[j+2], Wf1[(64+j+2)*HD + tid], p2);
      p3 = fmaf(rsh[j+3], Wf1[(64+j+3)*HD + tid], p3);
    }
    rw1sh[tid] = (p0+p1) + (p2+p3);
  }
  __syncthreads();

  // ================= Langevin step loop =================
  for (int st = 0; st < steps; ++st) {
    const float t = (float)st * dt;

    // noise prefetch (wave 0): issued here, consumed at the z-update — the
    // HBM/L2 latency hides under S0..S4.
    float noise_v = 0.f;
    if (tid < 64)
      noise_v = noises[(size_t)st * (B_TOT * ZD) + b * ZD + tid];

    // ---- S0: waves 0-1: zw1 + dec L1 (2 kc-slices each) || waves 2-3: f1
    if (w < 2) {
      // zw1[tid] = bd1[tid] + sum_j z[j] Wd1[j,tid]   (tid in [0,128))
      {
        float p0 = bd1[tid], p1 = 0.f, p2 = 0.f, p3 = 0.f;
        #pragma unroll 4
        for (int j = 0; j < 64; j += 4) {
          p0 = fmaf(zsh[j+0], Wd1[(j+0)*HD + tid], p0);
          p1 = fmaf(zsh[j+1], Wd1[(j+1)*HD + tid], p1);
          p2 = fmaf(zsh[j+2], Wd1[(j+2)*HD + tid], p2);
          p3 = fmaf(zsh[j+3], Wd1[(j+3)*HD + tid], p3);
        }
        zw1[tid] = (p0+p1) + (p2+p3);
      }
      wave_sync();   // wave w' wrote zw1[64w'..64w'+64); its dec L1 reads only those
      // dec L1: h1 = silu(zW1 + x*Wd1x) -> h1f, kc slices {2w, 2w+1}
      #pragma unroll
      for (int kq = 0; kq < 2; ++kq) {
        const int kcs = 2*w + kq;
        #pragma unroll
        for (int quad = 0; quad < 4; ++quad) {
          unsigned int pw[4];
          #pragma unroll
          for (int jj = 0; jj < 8; jj += 2) {
            const int k = 32*kcs + 8*quad + jj;
            const float sA = zw1[k]   + x0v*wx0sh[k]   + x1v*wx1sh[k];
            const float sB = zw1[k+1] + x0v*wx0sh[k+1] + x1v*wx1sh[k+1];
            pw[jj>>1] = packbf(sA*sigf(sA), sB*sigf(sB));
          }
          uint4 v4; v4.x = pw[0]; v4.y = pw[1]; v4.z = pw[2]; v4.w = pw[3];
          ((uint4*)h1f)[(kcs*4 + (lane>>4))*64 + quad*16 + (lane&15)] = v4;
        }
      }
    } else {
      // f1[o] = silu(rw1 + t*wt1 + z@Wf1_z)   (o in [0,128)) — r-part hoisted
      const int o = tid - 128;
      float p0 = fmaf(t, wt1sh[o], rw1sh[o]);
      float p1 = 0.f, p2 = 0.f, p3 = 0.f;
      #pragma unroll 4
      for (int j = 0; j < 64; j += 4) {
        p0 = fmaf(zsh[j+0], Wf1[(j+0)*HD + o], p0);
        p1 = fmaf(zsh[j+1], Wf1[(j+1)*HD + o], p1);
        p2 = fmaf(zsh[j+2], Wf1[(j+2)*HD + o], p2);
        p3 = fmaf(zsh[j+3], Wf1[(j+3)*HD + o], p3);
      }
      const float a = (p0+p1) + (p2+p3);
      f1sh[o] = a * sigf(a);
    }
    __syncthreads();   // B1: h1f (all kc slices) + f1sh ready

    // fwd (MFMA): S2 = H1 @ Wd2 + bd2; emit tau (-> h1f, wave-private slots)
    float ebw[4];
    {
      bh8 af[4];
      #pragma unroll
      for (int kc = 0; kc < 4; ++kc)
        af[kc] = ((const bh8*)h1f)[(kc*4 + w)*64 + lane];
      float da[4] = {0.f, 0.f, 0.f, 0.f};
      #pragma unroll 1
      for (int half = 0; half < 2; ++half) {
        const int h4 = half*4;
        fx4 acc[4];
        #pragma unroll
        for (int i = 0; i < 4; ++i) {
          const float bv = bd2sh[(h4+i)*16 + rr];
          acc[i] = (fx4){bv, bv, bv, bv};
        }
        #pragma unroll
        for (int i = 0; i < 4; ++i) {
          const int nt = h4 + i;
          const bh8 b0 = Wd2f[(0*8+nt)*64 + lane];
          const bh8 b1 = Wd2f[(1*8+nt)*64 + lane];
          const bh8 b2 = Wd2f[(2*8+nt)*64 + lane];
          const bh8 b3 = Wd2f[(3*8+nt)*64 + lane];
          acc[i] = __builtin_amdgcn_mfma_f32_16x16x32_bf16(af[0], b0, acc[i], 0,0,0);
          acc[i] = __builtin_amdgcn_mfma_f32_16x16x32_bf16(af[1], b1, acc[i], 0,0,0);
          acc[i] = __builtin_amdgcn_mfma_f32_16x16x32_bf16(af[2], b2, acc[i], 0,0,0);
          acc[i] = __builtin_amdgcn_mfma_f32_16x16x32_bf16(af[3], b3, acc[i], 0,0,0);
        }
        #pragma unroll
        for (int i = 0; i < 4; ++i) {
          const int nt = h4 + i;
          const float w3 = wd3sh[nt*16 + rr];
          #pragma unroll
          for (int g = 0; g < 4; ++g) {
            const float s2 = acc[i][g];
            const float sg = sigf(s2);
            da[g] = fmaf(s2*sg, w3, da[g]);
            const unsigned int tb = bfb(w3 * (sg * fmaf(s2, 1.0f - sg, 1.0f)));
            const unsigned int pb = (unsigned int)__shfl_xor((int)tb, 1, 64);
            if ((rr & 1) == 0) {
              const int unit = ((nt>>1)*4 + w)*64 + (2*(nt&1) + (rr>>3))*16 + 4*qq + g;
              h1f[unit*4 + ((rr&7)>>1)] = tb | (pb << 16);
            }
          }
        }
      }
      #pragma unroll
      for (int g = 0; g < 4; ++g) {
        float v = da[g];
        v += __shfl_xor(v, 1, 64);
        v += __shfl_xor(v, 2, 64);
        v += __shfl_xor(v, 4, 64);
        v += __shfl_xor(v, 8, 64);
        ebw[g] = t * mkq[g] * (v + bd3v - yq[g]);
      }
    }
    wave_sync();

    // bwd (MFMA): U = TAU @ Wd2^T; dsum[k] = colsum(ebw * silu'(s1) * U)
    {
      bh8 tf4[4];
      #pragma unroll
      for (int kc = 0; kc < 4; ++kc)
        tf4[kc] = ((const bh8*)h1f)[(kc*4 + w)*64 + lane];
      #pragma unroll 1
      for (int half = 0; half < 2; ++half) {
        const int h4 = half*4;
        fx4 u[4];
        #pragma unroll
        for (int i = 0; i < 4; ++i) u[i] = (fx4){0.f, 0.f, 0.f, 0.f};
        #pragma unroll
        for (int i = 0; i < 4; ++i) {
          const int nt = h4 + i;
          const bh8 b0 = Wd2Tf[(0*8+nt)*64 + lane];
          const bh8 b1 = Wd2Tf[(1*8+nt)*64 + lane];
          const bh8 b2 = Wd2Tf[(2*8+nt)*64 + lane];
          const bh8 b3 = Wd2Tf[(3*8+nt)*64 + lane];
          u[i] = __builtin_amdgcn_mfma_f32_16x16x32_bf16(tf4[0], b0, u[i], 0,0,0);
          u[i] = __builtin_amdgcn_mfma_f32_16x16x32_bf16(tf4[1], b1, u[i], 0,0,0);
          u[i] = __builtin_amdgcn_mfma_f32_16x16x32_bf16(tf4[2], b2, u[i], 0,0,0);
          u[i] = __builtin_amdgcn_mfma_f32_16x16x32_bf16(tf4[3], b3, u[i], 0,0,0);
        }
        #pragma unroll
        for (int i = 0; i < 4; ++i) {
          const int nt = h4 + i;
          const float zv = zw1[nt*16 + rr];
          const float wa = wx0sh[nt*16 + rr];
          const float wb = wx1sh[nt*16 + rr];
          float snt = 0.f;
          #pragma unroll
          for (int g = 0; g < 4; ++g) {
            const float s1 = zv + x0q[g]*wa + x1q[g]*wb;
            const float sg = sigf(s1);
            snt += ebw[g] * (sg * fmaf(s1, 1.0f - sg, 1.0f)) * u[i][g];
          }
          snt += __shfl_xor(snt, 16, 64);
          snt += __shfl_xor(snt, 32, 64);
          if (lane < 16) dsumP[w*128 + nt*16 + lane] = snt;
        }
      }
    }
    __syncthreads();   // B3: dsumP ready

    // ---- S3: tid<128: dsumC combine  ||  tid>=128: f2
    if (tid < 128) {
      dsumC[tid] = dsumP[tid] + dsumP[128+tid] + dsumP[256+tid] + dsumP[384+tid];
    } else {
      const int o = tid - 128;
      float p0 = bf2[o], p1 = 0.f, p2 = 0.f, p3 = 0.f;
      #pragma unroll 4
      for (int j = 0; j < 128; j += 4) {
        p0 = fmaf(f1sh[j+0], Wf2[(j+0)*HD + o], p0);
        p1 = fmaf(f1sh[j+1], Wf2[(j+1)*HD + o], p1);
        p2 = fmaf(f1sh[j+2], Wf2[(j+2)*HD + o], p2);
        p3 = fmaf(f1sh[j+3], Wf2[(j+3)*HD + o], p3);
      }
      const float a = (p0+p1) + (p2+p3);
      f2sh[o] = a * sigf(a);
    }
    __syncthreads();   // B4: dsumC + f2sh ready (dsumP now dead)

    // ---- S4 (2-way k-splits): tid<128: gz halves || tid>=128: f3 halves
    if (tid < 128) {
      const int j = tid & 63, h0 = (tid >> 6) * 64;
      float p0 = 0.f, p1 = 0.f, p2 = 0.f, p3 = 0.f;
      #pragma unroll 4
      for (int h = 0; h < 64; h += 4) {
        p0 = fmaf(dsumC[h0+h+0], Wd1[j*HD + h0+h+0], p0);
        p1 = fmaf(dsumC[h0+h+1], Wd1[j*HD + h0+h+1], p1);
        p2 = fmaf(dsumC[h0+h+2], Wd1[j*HD + h0+h+2], p2);
        p3 = fmaf(dsumC[h0+h+3], Wd1[j*HD + h0+h+3], p3);
      }
      dsumP[tid] = (p0+p1) + (p2+p3);            // gz partials (t in ebw)
    } else {
      const int o = tid - 128;
      const int j = o & 63, h0 = (o >> 6) * 64;
      float p0 = (h0 == 0) ? bf3[j] : 0.f;
      float p1 = 0.f, p2 = 0.f, p3 = 0.f;
      #pragma unroll 4
      for (int h = 0; h < 64; h += 4) {
        p0 = fmaf(f2sh[h0+h+0], Wf3[(h0+h+0)*ZD + j], p0);
        p1 = fmaf(f2sh[h0+h+1], Wf3[(h0+h+1)*ZD + j], p1);
        p2 = fmaf(f2sh[h0+h+2], Wf3[(h0+h+2)*ZD + j], p2);
        p3 = fmaf(f2sh[h0+h+3], Wf3[(h0+h+3)*ZD + j], p3);
      }
      bgz[o] = (p0+p1) + (p2+p3);                // f3 partials
    }
    __syncthreads();   // B5: partials ready

    if (tid < 64) {
      const float bdrift = bgz[tid] + bgz[64 + tid];
      const float gz     = dsumP[tid] + dsumP[64 + tid];
      const float zold = zsh[tid];
      float g = zold + gz;
      g = fminf(fmaxf(g, -100.0f), 100.0f);
      zsh[tid] = zold + (bdrift - g) * dt + dco * noise_v;
    }
    __syncthreads();   // B6: zsh ready for next step
  }

  if (tid < 64) out[b * ZD + tid] = zsh[tid];
}

extern "C" void kernel_launch(void* const* d_in, const int* in_sizes, int n_in,
                              void* d_out, int out_size, void* d_ws, size_t ws_size,
                              hipStream_t stream) {
  const float* x_ctx  = (const float*)d_in[0];
  const float* y_ctx  = (const float*)d_in[1];
  const float* mask   = (const float*)d_in[2];
  const float* z0     = (const float*)d_in[3];
  const float* noises = (const float*)d_in[4];
  const float* We1 = (const float*)d_in[5];  const float* be1 = (const float*)d_in[6];
  const float* We2 = (const float*)d_in[7];  const float* be2 = (const float*)d_in[8];
  const float* We3 = (const float*)d_in[9];  const float* be3 = (const float*)d_in[10];
  const float* Wd1 = (const float*)d_in[11]; const float* bd1 = (const float*)d_in[12];
  const float* Wd2 = (const float*)d_in[13]; const float* bd2 = (const float*)d_in[14];
  const float* Wd3 = (const float*)d_in[15]; const float* bd3 = (const float*)d_in[16];
  const float* Wf1 = (const float*)d_in[17]; const float* bf1 = (const float*)d_in[18];
  const float* Wf2 = (const float*)d_in[19]; const float* bf2 = (const float*)d_in[20];
  const float* Wf3 = (const float*)d_in[21]; const float* bf3 = (const float*)d_in[22];

  const int steps = in_sizes[4] / (B_TOT * ZD);
  const float dt  = 1.0f / (float)steps;
  const float dco = (float)sqrt(2.0 / (double)steps);

  ushort* wsu = (ushort*)d_ws;   // 4 bf16 frag arrays, 128 KB total

  hipLaunchKernelGGL(prep_kernel, dim3(256), dim3(256), 0, stream, Wd2, We2, We3, wsu);
  hipLaunchKernelGGL(metanets_kernel, dim3(B_TOT), dim3(256), 0, stream,
      x_ctx, y_ctx, mask, z0, noises,
      We1, be1, be2, be3,
      Wd1, bd1, bd2, Wd3, bd3,
      Wf1, bf1, Wf2, bf2, Wf3, bf3,
      wsu, (float*)d_out, steps, dt, dco);
}

// Round 5
// 965.789 us; speedup vs baseline: 1.3724x; 1.1565x over previous
//
#include <hip/hip_runtime.h>
#include <math.h>

// MetaNETS Langevin sampler, MI355X — round 10: register diet -> 4-wave bin.
// R9 post-mortem: occupancy pinned at ~32% (≈3 waves/SIMD) across rounds while
// arch VGPR=80 — the MFMA acc/frag pressure (unified VGPR/AGPR file) pushes
// true peak past 128 into the 3-wave bin. This round:
//  (1) all four MFMA phases (encL2/encL3/fwd/bwd) restructured to process
//      nt-tiles in PAIRS with immediate epilogues: 8 B-frags + 2 accs live
//      instead of 16 B-frags + 4 accs. Peak live drops ~24-32 regs.
//  (2) __launch_bounds__(256, 4): request 4 waves/EU (128-reg cap) now that
//      natural pressure fits. ILP->TLP trade: +1 resident wave/SIMD hides the
//      shorter in-wave MFMA chains.
// Everything else identical to R9 (wave-role overlap, rW1 hoist, tail splits,
// tau/h1f aliasing).

#define B_TOT 2048
#define NPT   64
#define ZD    64
#define HD    128

typedef short bh8 __attribute__((ext_vector_type(8)));   // 8 x bf16 (4 VGPR)
typedef float fx4 __attribute__((ext_vector_type(4)));   // MFMA C/D

__device__ __forceinline__ float sigf(float x) {
  return __builtin_amdgcn_rcpf(1.0f + __expf(-x));
}
__device__ __forceinline__ unsigned int bfb(float x) {   // fp32 -> bf16 bits (RNE)
  unsigned int u = __float_as_uint(x);
  u += 0x7FFFu + ((u >> 16) & 1u);
  return u >> 16;
}
__device__ __forceinline__ unsigned int packbf(float a, float b) {
  unsigned int ua = __float_as_uint(a), ub = __float_as_uint(b);
  ua += 0x7FFFu + ((ua >> 16) & 1u);
  ub += 0x7FFFu + ((ub >> 16) & 1u);
  return (ua >> 16) | (ub & 0xFFFF0000u);
}
__device__ __forceinline__ float wsum64(float v) {
  #pragma unroll
  for (int d = 1; d < 64; d <<= 1) v += __shfl_xor(v, d, 64);
  return v;
}
__device__ __forceinline__ void wave_sync() {   // intra-wave LDS order + drain
  __builtin_amdgcn_wave_barrier();
  __builtin_amdgcn_s_waitcnt(0xC07F);           // lgkmcnt(0)
  __builtin_amdgcn_wave_barrier();
}

// B-frag arrays (bf16): for W[K=128][N=128] with K = contraction:
//   frag[((kc*8+nt)*64 + L)*8 + j] = W[kc*32 + (L>>4)*8 + j][nt*16 + (L&15)]
// arr0: Wd2 (fwd)   arr1: Wd2^T (bwd)   arr2: We2   arr3: We3
__global__ __launch_bounds__(256)
void prep_kernel(const float* __restrict__ Wd2, const float* __restrict__ We2,
                 const float* __restrict__ We3, ushort* __restrict__ ws) {
  const int id = blockIdx.x * 256 + threadIdx.x;   // 65536 total
  const int arr = id >> 14;
  const int e = id & 16383;
  const int j = e & 7, L = (e >> 3) & 63, nt = (e >> 9) & 7, kc = e >> 12;
  const int kk = kc * 32 + (L >> 4) * 8 + j, nn = nt * 16 + (L & 15);
  float v;
  if      (arr == 0) v = Wd2[kk * HD + nn];
  else if (arr == 1) v = Wd2[nn * HD + kk];    // Wd2^T
  else if (arr == 2) v = We2[kk * HD + nn];
  else               v = We3[kk * HD + nn];
  ws[id] = (ushort)bfb(v);
}

__global__ __launch_bounds__(256, 4)
void metanets_kernel(
    const float* __restrict__ x_ctx, const float* __restrict__ y_ctx,
    const float* __restrict__ mask,  const float* __restrict__ z0,
    const float* __restrict__ noises,
    const float* __restrict__ We1, const float* __restrict__ be1,
    const float* __restrict__ be2, const float* __restrict__ be3,
    const float* __restrict__ Wd1, const float* __restrict__ bd1,
    const float* __restrict__ bd2, const float* __restrict__ Wd3,
    const float* __restrict__ bd3,
    const float* __restrict__ Wf1, const float* __restrict__ bf1,
    const float* __restrict__ Wf2, const float* __restrict__ bf2,
    const float* __restrict__ Wf3, const float* __restrict__ bf3,
    const ushort* __restrict__ wsfrag,
    float* __restrict__ out, int steps, float dt, float dco)
{
  // h1f doubles as the tau buffer (R7 invariant): within fwd/bwd every wave
  // touches only slots == w (mod 4) and A-frags are reg-loaded before the tau
  // scatter overwrites them.
  __shared__ unsigned int h1f[4096];    // A-frag units: [(slot)*64 + lane] x 4 dw
  __shared__ float zsh[64];
  __shared__ float zw1[128];
  __shared__ float rsh[128];
  __shared__ float dsumP[512];
  __shared__ float dsumC[128];
  __shared__ float f1sh[128];           // be2 staging, then drift hidden1
  __shared__ float f2sh[128];           // be3 staging, then drift hidden2
  __shared__ float bgz[128];            // f3 k-split partials (2x64)
  __shared__ float rw1sh[128];          // bf1 + r @ Wf1_r (step-invariant)
  __shared__ float wt1sh[128];          // Wf1 t-row staged
  __shared__ float bd2sh[128], wd3sh[128], wx0sh[128], wx1sh[128];

  const int tid = threadIdx.x;
  const int lane = tid & 63;                                  // context point
  const int w = __builtin_amdgcn_readfirstlane(tid >> 6);     // wave = m-tile
  const int b = blockIdx.x;
  const int rr = lane & 15, qq = lane >> 4;

  const bh8* Wd2f  = (const bh8*)(wsfrag);
  const bh8* Wd2Tf = (const bh8*)(wsfrag + 16384);
  const bh8* We2f  = (const bh8*)(wsfrag + 32768);
  const bh8* We3f  = (const bh8*)(wsfrag + 49152);

  const float x0v = x_ctx[(b*NPT + lane)*2 + 0];
  const float x1v = x_ctx[(b*NPT + lane)*2 + 1];
  const float yv  = y_ctx[b*NPT + lane];
  const float mkv = mask[b*NPT + lane];
  const float inv_msum = 1.0f / fmaxf(wsum64(mkv), 1e-6f);
  const float bd3v = bd3[0];

  // per-lane data for the 4 C-rows this lane holds (points 16w+4*qq+g)
  float x0q[4], x1q[4], yq[4], mkq[4];
  #pragma unroll
  for (int g = 0; g < 4; ++g) {
    const int src = (w << 4) | (qq << 2) | g;
    x0q[g] = __shfl(x0v, src, 64);
    x1q[g] = __shfl(x1v, src, 64);
    yq[g]  = __shfl(yv,  src, 64);
    mkq[g] = __shfl(mkv, src, 64);
  }

  if (tid < 64) zsh[tid] = z0[b*ZD + tid];
  if (tid < 128) {
    bd2sh[tid] = bd2[tid];
    wd3sh[tid] = Wd3[tid];
    wx0sh[tid] = Wd1[64*HD + tid];
    wx1sh[tid] = Wd1[65*HD + tid];
    f1sh[tid]  = be2[tid];
    f2sh[tid]  = be3[tid];
    wt1sh[tid] = Wf1[192*HD + tid];
  }
  __syncthreads();

  // ================= encoder =================
  // enc L1: lane=point, wave w computes k-slice kc=w, writes A-frag layout
  #pragma unroll
  for (int quad = 0; quad < 4; ++quad) {
    unsigned int pw[4];
    #pragma unroll
    for (int jj = 0; jj < 8; jj += 2) {
      const int k = 32*w + 8*quad + jj;
      const float sA = be1[k]   + x0v*We1[k]   + x1v*We1[HD+k]   + yv*We1[2*HD+k];
      const float sB = be1[k+1] + x0v*We1[k+1] + x1v*We1[HD+k+1] + yv*We1[2*HD+k+1];
      pw[jj>>1] = packbf(sA*sigf(sA), sB*sigf(sB));
    }
    uint4 v4; v4.x = pw[0]; v4.y = pw[1]; v4.z = pw[2]; v4.w = pw[3];
    ((uint4*)h1f)[(w*4 + (lane>>4))*64 + quad*16 + (lane&15)] = v4;
  }
  __syncthreads();

  // enc L2 (MFMA): H2 = silu(H1 @ We2 + be2) -> tau (A-frag layout, in h1f)
  // pair-processed: 8 B-frags + 2 accs live, immediate epilogue per nt.
  {
    bh8 af[4];
    #pragma unroll
    for (int kc = 0; kc < 4; ++kc)
      af[kc] = ((const bh8*)h1f)[(kc*4 + w)*64 + lane];
    #pragma unroll 1
    for (int np = 0; np < 4; ++np) {
      const int nt0 = 2*np, nt1 = 2*np + 1;
      const bh8 a0 = We2f[(0*8+nt0)*64 + lane];
      const bh8 a1 = We2f[(1*8+nt0)*64 + lane];
      const bh8 a2 = We2f[(2*8+nt0)*64 + lane];
      const bh8 a3 = We2f[(3*8+nt0)*64 + lane];
      const bh8 c0 = We2f[(0*8+nt1)*64 + lane];
      const bh8 c1 = We2f[(1*8+nt1)*64 + lane];
      const bh8 c2 = We2f[(2*8+nt1)*64 + lane];
      const bh8 c3 = We2f[(3*8+nt1)*64 + lane];
      const float bv0 = f1sh[nt0*16 + rr], bv1 = f1sh[nt1*16 + rr];
      fx4 acc0 = (fx4){bv0, bv0, bv0, bv0};
      fx4 acc1 = (fx4){bv1, bv1, bv1, bv1};
      acc0 = __builtin_amdgcn_mfma_f32_16x16x32_bf16(af[0], a0, acc0, 0,0,0);
      acc1 = __builtin_amdgcn_mfma_f32_16x16x32_bf16(af[0], c0, acc1, 0,0,0);
      acc0 = __builtin_amdgcn_mfma_f32_16x16x32_bf16(af[1], a1, acc0, 0,0,0);
      acc1 = __builtin_amdgcn_mfma_f32_16x16x32_bf16(af[1], c1, acc1, 0,0,0);
      acc0 = __builtin_amdgcn_mfma_f32_16x16x32_bf16(af[2], a2, acc0, 0,0,0);
      acc1 = __builtin_amdgcn_mfma_f32_16x16x32_bf16(af[2], c2, acc1, 0,0,0);
      acc0 = __builtin_amdgcn_mfma_f32_16x16x32_bf16(af[3], a3, acc0, 0,0,0);
      acc1 = __builtin_amdgcn_mfma_f32_16x16x32_bf16(af[3], c3, acc1, 0,0,0);
      #pragma unroll
      for (int pi = 0; pi < 2; ++pi) {
        const int nt = pi ? nt1 : nt0;
        const fx4 acc = pi ? acc1 : acc0;
        #pragma unroll
        for (int g = 0; g < 4; ++g) {
          const float s2 = acc[g];
          const unsigned int tb = bfb(s2 * sigf(s2));
          const unsigned int pb = (unsigned int)__shfl_xor((int)tb, 1, 64);
          if ((rr & 1) == 0) {
            const int unit = ((nt>>1)*4 + w)*64 + (2*(nt&1) + (rr>>3))*16 + 4*qq + g;
            h1f[unit*4 + ((rr&7)>>1)] = tb | (pb << 16);
          }
        }
      }
    }
  }
  wave_sync();

  // enc L3 (MFMA) + masked mean-pool -> rsh (pair-processed)
  {
    bh8 tf4[4];
    #pragma unroll
    for (int kc = 0; kc < 4; ++kc)
      tf4[kc] = ((const bh8*)h1f)[(kc*4 + w)*64 + lane];
    #pragma unroll 1
    for (int np = 0; np < 4; ++np) {
      const int nt0 = 2*np, nt1 = 2*np + 1;
      const bh8 a0 = We3f[(0*8+nt0)*64 + lane];
      const bh8 a1 = We3f[(1*8+nt0)*64 + lane];
      const bh8 a2 = We3f[(2*8+nt0)*64 + lane];
      const bh8 a3 = We3f[(3*8+nt0)*64 + lane];
      const bh8 c0 = We3f[(0*8+nt1)*64 + lane];
      const bh8 c1 = We3f[(1*8+nt1)*64 + lane];
      const bh8 c2 = We3f[(2*8+nt1)*64 + lane];
      const bh8 c3 = We3f[(3*8+nt1)*64 + lane];
      const float bv0 = f2sh[nt0*16 + rr], bv1 = f2sh[nt1*16 + rr];
      fx4 acc0 = (fx4){bv0, bv0, bv0, bv0};
      fx4 acc1 = (fx4){bv1, bv1, bv1, bv1};
      acc0 = __builtin_amdgcn_mfma_f32_16x16x32_bf16(tf4[0], a0, acc0, 0,0,0);
      acc1 = __builtin_amdgcn_mfma_f32_16x16x32_bf16(tf4[0], c0, acc1, 0,0,0);
      acc0 = __builtin_amdgcn_mfma_f32_16x16x32_bf16(tf4[1], a1, acc0, 0,0,0);
      acc1 = __builtin_amdgcn_mfma_f32_16x16x32_bf16(tf4[1], c1, acc1, 0,0,0);
      acc0 = __builtin_amdgcn_mfma_f32_16x16x32_bf16(tf4[2], a2, acc0, 0,0,0);
      acc1 = __builtin_amdgcn_mfma_f32_16x16x32_bf16(tf4[2], c2, acc1, 0,0,0);
      acc0 = __builtin_amdgcn_mfma_f32_16x16x32_bf16(tf4[3], a3, acc0, 0,0,0);
      acc1 = __builtin_amdgcn_mfma_f32_16x16x32_bf16(tf4[3], c3, acc1, 0,0,0);
      #pragma unroll
      for (int pi = 0; pi < 2; ++pi) {
        const int nt = pi ? nt1 : nt0;
        const fx4 acc = pi ? acc1 : acc0;
        float pv = mkq[0]*acc[0] + mkq[1]*acc[1]
                 + mkq[2]*acc[2] + mkq[3]*acc[3];
        pv += __shfl_xor(pv, 16, 64);
        pv += __shfl_xor(pv, 32, 64);
        if (lane < 16) dsumP[w*128 + nt*16 + lane] = pv;
      }
    }
  }
  __syncthreads();
  if (tid < 128)
    rsh[tid] = (dsumP[tid] + dsumP[128+tid] + dsumP[256+tid] + dsumP[384+tid]) * inv_msum;
  __syncthreads();

  // rW1 precompute (once): rw1sh = bf1 + r @ Wf1_r  (step-invariant part of f1)
  if (tid < 128) {
    float p0 = bf1[tid], p1 = 0.f, p2 = 0.f, p3 = 0.f;
    #pragma unroll 4
    for (int j = 0; j < 128; j += 4) {
      p0 = fmaf(rsh[j+0], Wf1[(64+j+0)*HD + tid], p0);
      p1 = fmaf(rsh[j+1], Wf1[(64+j+1)*HD + tid], p1);
      p2 = fmaf(rsh[j+2], Wf1[(64+j+2)*HD + tid], p2);
      p3 = fmaf(rsh[j+3], Wf1[(64+j+3)*HD + tid], p3);
    }
    rw1sh[tid] = (p0+p1) + (p2+p3);
  }
  __syncthreads();

  // ================= Langevin step loop =================
  for (int st = 0; st < steps; ++st) {
    const float t = (float)st * dt;

    // noise prefetch (wave 0): issued here, consumed at the z-update.
    float noise_v = 0.f;
    if (tid < 64)
      noise_v = noises[(size_t)st * (B_TOT * ZD) + b * ZD + tid];

    // ---- S0: waves 0-1: zw1 + dec L1 (2 kc-slices each) || waves 2-3: f1
    if (w < 2) {
      {
        float p0 = bd1[tid], p1 = 0.f, p2 = 0.f, p3 = 0.f;
        #pragma unroll 4
        for (int j = 0; j < 64; j += 4) {
          p0 = fmaf(zsh[j+0], Wd1[(j+0)*HD + tid], p0);
          p1 = fmaf(zsh[j+1], Wd1[(j+1)*HD + tid], p1);
          p2 = fmaf(zsh[j+2], Wd1[(j+2)*HD + tid], p2);
          p3 = fmaf(zsh[j+3], Wd1[(j+3)*HD + tid], p3);
        }
        zw1[tid] = (p0+p1) + (p2+p3);
      }
      wave_sync();   // wave w' wrote zw1[64w'..64w'+64); its dec L1 reads only those
      #pragma unroll
      for (int kq = 0; kq < 2; ++kq) {
        const int kcs = 2*w + kq;
        #pragma unroll
        for (int quad = 0; quad < 4; ++quad) {
          unsigned int pw[4];
          #pragma unroll
          for (int jj = 0; jj < 8; jj += 2) {
            const int k = 32*kcs + 8*quad + jj;
            const float sA = zw1[k]   + x0v*wx0sh[k]   + x1v*wx1sh[k];
            const float sB = zw1[k+1] + x0v*wx0sh[k+1] + x1v*wx1sh[k+1];
            pw[jj>>1] = packbf(sA*sigf(sA), sB*sigf(sB));
          }
          uint4 v4; v4.x = pw[0]; v4.y = pw[1]; v4.z = pw[2]; v4.w = pw[3];
          ((uint4*)h1f)[(kcs*4 + (lane>>4))*64 + quad*16 + (lane&15)] = v4;
        }
      }
    } else {
      // f1[o] = silu(rw1 + t*wt1 + z@Wf1_z)   (o in [0,128)) — r-part hoisted
      const int o = tid - 128;
      float p0 = fmaf(t, wt1sh[o], rw1sh[o]);
      float p1 = 0.f, p2 = 0.f, p3 = 0.f;
      #pragma unroll 4
      for (int j = 0; j < 64; j += 4) {
        p0 = fmaf(zsh[j+0], Wf1[(j+0)*HD + o], p0);
        p1 = fmaf(zsh[j+1], Wf1[(j+1)*HD + o], p1);
        p2 = fmaf(zsh[j+2], Wf1[(j+2)*HD + o], p2);
        p3 = fmaf(zsh[j+3], Wf1[(j+3)*HD + o], p3);
      }
      const float a = (p0+p1) + (p2+p3);
      f1sh[o] = a * sigf(a);
    }
    __syncthreads();   // B1: h1f (all kc slices) + f1sh ready

    // fwd (MFMA): S2 = H1 @ Wd2 + bd2; emit tau (-> h1f, wave-private slots)
    // pair-processed: 8 B-frags + 2 accs live.
    float ebw[4];
    {
      bh8 af[4];
      #pragma unroll
      for (int kc = 0; kc < 4; ++kc)
        af[kc] = ((const bh8*)h1f)[(kc*4 + w)*64 + lane];
      float da[4] = {0.f, 0.f, 0.f, 0.f};
      #pragma unroll 1
      for (int np = 0; np < 4; ++np) {
        const int nt0 = 2*np, nt1 = 2*np + 1;
        const bh8 a0 = Wd2f[(0*8+nt0)*64 + lane];
        const bh8 a1 = Wd2f[(1*8+nt0)*64 + lane];
        const bh8 a2 = Wd2f[(2*8+nt0)*64 + lane];
        const bh8 a3 = Wd2f[(3*8+nt0)*64 + lane];
        const bh8 c0 = Wd2f[(0*8+nt1)*64 + lane];
        const bh8 c1 = Wd2f[(1*8+nt1)*64 + lane];
        const bh8 c2 = Wd2f[(2*8+nt1)*64 + lane];
        const bh8 c3 = Wd2f[(3*8+nt1)*64 + lane];
        const float bv0 = bd2sh[nt0*16 + rr], bv1 = bd2sh[nt1*16 + rr];
        fx4 acc0 = (fx4){bv0, bv0, bv0, bv0};
        fx4 acc1 = (fx4){bv1, bv1, bv1, bv1};
        acc0 = __builtin_amdgcn_mfma_f32_16x16x32_bf16(af[0], a0, acc0, 0,0,0);
        acc1 = __builtin_amdgcn_mfma_f32_16x16x32_bf16(af[0], c0, acc1, 0,0,0);
        acc0 = __builtin_amdgcn_mfma_f32_16x16x32_bf16(af[1], a1, acc0, 0,0,0);
        acc1 = __builtin_amdgcn_mfma_f32_16x16x32_bf16(af[1], c1, acc1, 0,0,0);
        acc0 = __builtin_amdgcn_mfma_f32_16x16x32_bf16(af[2], a2, acc0, 0,0,0);
        acc1 = __builtin_amdgcn_mfma_f32_16x16x32_bf16(af[2], c2, acc1, 0,0,0);
        acc0 = __builtin_amdgcn_mfma_f32_16x16x32_bf16(af[3], a3, acc0, 0,0,0);
        acc1 = __builtin_amdgcn_mfma_f32_16x16x32_bf16(af[3], c3, acc1, 0,0,0);
        #pragma unroll
        for (int pi = 0; pi < 2; ++pi) {
          const int nt = pi ? nt1 : nt0;
          const fx4 acc = pi ? acc1 : acc0;
          const float w3 = wd3sh[nt*16 + rr];
          #pragma unroll
          for (int g = 0; g < 4; ++g) {
            const float s2 = acc[g];
            const float sg = sigf(s2);
            da[g] = fmaf(s2*sg, w3, da[g]);
            const unsigned int tb = bfb(w3 * (sg * fmaf(s2, 1.0f - sg, 1.0f)));
            const unsigned int pb = (unsigned int)__shfl_xor((int)tb, 1, 64);
            if ((rr & 1) == 0) {
              const int unit = ((nt>>1)*4 + w)*64 + (2*(nt&1) + (rr>>3))*16 + 4*qq + g;
              h1f[unit*4 + ((rr&7)>>1)] = tb | (pb << 16);
            }
          }
        }
      }
      #pragma unroll
      for (int g = 0; g < 4; ++g) {
        float v = da[g];
        v += __shfl_xor(v, 1, 64);
        v += __shfl_xor(v, 2, 64);
        v += __shfl_xor(v, 4, 64);
        v += __shfl_xor(v, 8, 64);
        ebw[g] = t * mkq[g] * (v + bd3v - yq[g]);
      }
    }
    wave_sync();

    // bwd (MFMA): U = TAU @ Wd2^T; dsum[k] = colsum(ebw * silu'(s1) * U)
    // pair-processed.
    {
      bh8 tf4[4];
      #pragma unroll
      for (int kc = 0; kc < 4; ++kc)
        tf4[kc] = ((const bh8*)h1f)[(kc*4 + w)*64 + lane];
      #pragma unroll 1
      for (int np = 0; np < 4; ++np) {
        const int nt0 = 2*np, nt1 = 2*np + 1;
        const bh8 a0 = Wd2Tf[(0*8+nt0)*64 + lane];
        const bh8 a1 = Wd2Tf[(1*8+nt0)*64 + lane];
        const bh8 a2 = Wd2Tf[(2*8+nt0)*64 + lane];
        const bh8 a3 = Wd2Tf[(3*8+nt0)*64 + lane];
        const bh8 c0 = Wd2Tf[(0*8+nt1)*64 + lane];
        const bh8 c1 = Wd2Tf[(1*8+nt1)*64 + lane];
        const bh8 c2 = Wd2Tf[(2*8+nt1)*64 + lane];
        const bh8 c3 = Wd2Tf[(3*8+nt1)*64 + lane];
        fx4 u0 = (fx4){0.f, 0.f, 0.f, 0.f};
        fx4 u1 = (fx4){0.f, 0.f, 0.f, 0.f};
        u0 = __builtin_amdgcn_mfma_f32_16x16x32_bf16(tf4[0], a0, u0, 0,0,0);
        u1 = __builtin_amdgcn_mfma_f32_16x16x32_bf16(tf4[0], c0, u1, 0,0,0);
        u0 = __builtin_amdgcn_mfma_f32_16x16x32_bf16(tf4[1], a1, u0, 0,0,0);
        u1 = __builtin_amdgcn_mfma_f32_16x16x32_bf16(tf4[1], c1, u1, 0,0,0);
        u0 = __builtin_amdgcn_mfma_f32_16x16x32_bf16(tf4[2], a2, u0, 0,0,0);
        u1 = __builtin_amdgcn_mfma_f32_16x16x32_bf16(tf4[2], c2, u1, 0,0,0);
        u0 = __builtin_amdgcn_mfma_f32_16x16x32_bf16(tf4[3], a3, u0, 0,0,0);
        u1 = __builtin_amdgcn_mfma_f32_16x16x32_bf16(tf4[3], c3, u1, 0,0,0);
        #pragma unroll
        for (int pi = 0; pi < 2; ++pi) {
          const int nt = pi ? nt1 : nt0;
          const fx4 u = pi ? u1 : u0;
          const float zv = zw1[nt*16 + rr];
          const float wa = wx0sh[nt*16 + rr];
          const float wb = wx1sh[nt*16 + rr];
          float snt = 0.f;
          #pragma unroll
          for (int g = 0; g < 4; ++g) {
            const float s1 = zv + x0q[g]*wa + x1q[g]*wb;
            const float sg = sigf(s1);
            snt += ebw[g] * (sg * fmaf(s1, 1.0f - sg, 1.0f)) * u[g];
          }
          snt += __shfl_xor(snt, 16, 64);
          snt += __shfl_xor(snt, 32, 64);
          if (lane < 16) dsumP[w*128 + nt*16 + lane] = snt;
        }
      }
    }
    __syncthreads();   // B3: dsumP ready

    // ---- S3: tid<128: dsumC combine  ||  tid>=128: f2
    if (tid < 128) {
      dsumC[tid] = dsumP[tid] + dsumP[128+tid] + dsumP[256+tid] + dsumP[384+tid];
    } else {
      const int o = tid - 128;
      float p0 = bf2[o], p1 = 0.f, p2 = 0.f, p3 = 0.f;
      #pragma unroll 4
      for (int j = 0; j < 128; j += 4) {
        p0 = fmaf(f1sh[j+0], Wf2[(j+0)*HD + o], p0);
        p1 = fmaf(f1sh[j+1], Wf2[(j+1)*HD + o], p1);
        p2 = fmaf(f1sh[j+2], Wf2[(j+2)*HD + o], p2);
        p3 = fmaf(f1sh[j+3], Wf2[(j+3)*HD + o], p3);
      }
      const float a = (p0+p1) + (p2+p3);
      f2sh[o] = a * sigf(a);
    }
    __syncthreads();   // B4: dsumC + f2sh ready

    // ---- S4 (2-way k-splits): tid<128: gz halves || tid>=128: f3 halves
    if (tid < 128) {
      const int j = tid & 63, h0 = (tid >> 6) * 64;
      float p0 = 0.f, p1 = 0.f, p2 = 0.f, p3 = 0.f;
      #pragma unroll 4
      for (int h = 0; h < 64; h += 4) {
        p0 = fmaf(dsumC[h0+h+0], Wd1[j*HD + h0+h+0], p0);
        p1 = fmaf(dsumC[h0+h+1], Wd1[j*HD + h0+h+1], p1);
        p2 = fmaf(dsumC[h0+h+2], Wd1[j*HD + h0+h+2], p2);
        p3 = fmaf(dsumC[h0+h+3], Wd1[j*HD + h0+h+3], p3);
      }
      dsumP[tid] = (p0+p1) + (p2+p3);            // gz partials (t in ebw)
    } else {
      const int o = tid - 128;
      const int j = o & 63, h0 = (o >> 6) * 64;
      float p0 = (h0 == 0) ? bf3[j] : 0.f;
      float p1 = 0.f, p2 = 0.f, p3 = 0.f;
      #pragma unroll 4
      for (int h = 0; h < 64; h += 4) {
        p0 = fmaf(f2sh[h0+h+0], Wf3[(h0+h+0)*ZD + j], p0);
        p1 = fmaf(f2sh[h0+h+1], Wf3[(h0+h+1)*ZD + j], p1);
        p2 = fmaf(f2sh[h0+h+2], Wf3[(h0+h+2)*ZD + j], p2);
        p3 = fmaf(f2sh[h0+h+3], Wf3[(h0+h+3)*ZD + j], p3);
      }
      bgz[o] = (p0+p1) + (p2+p3);                // f3 partials
    }
    __syncthreads();   // B5: partials ready

    if (tid < 64) {
      const float bdrift = bgz[tid] + bgz[64 + tid];
      const float gz     = dsumP[tid] + dsumP[64 + tid];
      const float zold = zsh[tid];
      float g = zold + gz;
      g = fminf(fmaxf(g, -100.0f), 100.0f);
      zsh[tid] = zold + (bdrift - g) * dt + dco * noise_v;
    }
    __syncthreads();   // B6: zsh ready for next step
  }

  if (tid < 64) out[b * ZD + tid] = zsh[tid];
}

extern "C" void kernel_launch(void* const* d_in, const int* in_sizes, int n_in,
                              void* d_out, int out_size, void* d_ws, size_t ws_size,
                              hipStream_t stream) {
  const float* x_ctx  = (const float*)d_in[0];
  const float* y_ctx  = (const float*)d_in[1];
  const float* mask   = (const float*)d_in[2];
  const float* z0     = (const float*)d_in[3];
  const float* noises = (const float*)d_in[4];
  const float* We1 = (const float*)d_in[5];  const float* be1 = (const float*)d_in[6];
  const float* We2 = (const float*)d_in[7];  const float* be2 = (const float*)d_in[8];
  const float* We3 = (const float*)d_in[9];  const float* be3 = (const float*)d_in[10];
  const float* Wd1 = (const float*)d_in[11]; const float* bd1 = (const float*)d_in[12];
  const float* Wd2 = (const float*)d_in[13]; const float* bd2 = (const float*)d_in[14];
  const float* Wd3 = (const float*)d_in[15]; const float* bd3 = (const float*)d_in[16];
  const float* Wf1 = (const float*)d_in[17]; const float* bf1 = (const float*)d_in[18];
  const float* Wf2 = (const float*)d_in[19]; const float* bf2 = (const float*)d_in[20];
  const float* Wf3 = (const float*)d_in[21]; const float* bf3 = (const float*)d_in[22];

  const int steps = in_sizes[4] / (B_TOT * ZD);
  const float dt  = 1.0f / (float)steps;
  const float dco = (float)sqrt(2.0 / (double)steps);

  ushort* wsu = (ushort*)d_ws;   // 4 bf16 frag arrays, 128 KB total

  hipLaunchKernelGGL(prep_kernel, dim3(256), dim3(256), 0, stream, Wd2, We2, We3, wsu);
  hipLaunchKernelGGL(metanets_kernel, dim3(B_TOT), dim3(256), 0, stream,
      x_ctx, y_ctx, mask, z0, noises,
      We1, be1, be2, be3,
      Wd1, bd1, bd2, Wd3, bd3,
      Wf1, bf1, Wf2, bf2, Wf3, bf3,
      wsu, (float*)d_out, steps, dt, dco);
}

// Round 7
// 933.841 us; speedup vs baseline: 1.4194x; 1.0342x over previous
//
#include <hip/hip_runtime.h>
#include <math.h>

// MetaNETS Langevin sampler, MI355X — round 12: R11 + zold RMW-race fix.
// R11 post-mortem (FAILED, absmax 0.94): the redundant z-update raced —
// fast wave writes zsh[zi]=V_new before slow wave reads zold=V_old (RMW on
// shared zsh). Fix: read zold into a REGISTER at the top of the step (zsh is
// stable from step-top until the post-B5 update; only same-value late writes
// from the previous update are in flight). After B5 every wave then computes
// identical values from registers + barriered LDS and performs benign
// same-value writes; trailing wave_sync suffices.
// Keeps R11's structure: balanced phase A (zw1 || f1), dec-L1 on all 4 waves,
// S3->S4 wave-aligned wave_sync, 4 syncthreads + 3 wave_sync per step,
// pair-processed MFMA, (256,4), rW1 hoist, tau/h1f aliasing, tail k-splits.

#define B_TOT 2048
#define NPT   64
#define ZD    64
#define HD    128

typedef short bh8 __attribute__((ext_vector_type(8)));   // 8 x bf16 (4 VGPR)
typedef float fx4 __attribute__((ext_vector_type(4)));   // MFMA C/D

__device__ __forceinline__ float sigf(float x) {
  return __builtin_amdgcn_rcpf(1.0f + __expf(-x));
}
__device__ __forceinline__ unsigned int bfb(float x) {   // fp32 -> bf16 bits (RNE)
  unsigned int u = __float_as_uint(x);
  u += 0x7FFFu + ((u >> 16) & 1u);
  return u >> 16;
}
__device__ __forceinline__ unsigned int packbf(float a, float b) {
  unsigned int ua = __float_as_uint(a), ub = __float_as_uint(b);
  ua += 0x7FFFu + ((ua >> 16) & 1u);
  ub += 0x7FFFu + ((ub >> 16) & 1u);
  return (ua >> 16) | (ub & 0xFFFF0000u);
}
__device__ __forceinline__ float wsum64(float v) {
  #pragma unroll
  for (int d = 1; d < 64; d <<= 1) v += __shfl_xor(v, d, 64);
  return v;
}
__device__ __forceinline__ void wave_sync() {   // intra-wave LDS order + drain
  __builtin_amdgcn_wave_barrier();
  __builtin_amdgcn_s_waitcnt(0xC07F);           // lgkmcnt(0)
  __builtin_amdgcn_wave_barrier();
}

// B-frag arrays (bf16): for W[K=128][N=128] with K = contraction:
//   frag[((kc*8+nt)*64 + L)*8 + j] = W[kc*32 + (L>>4)*8 + j][nt*16 + (L&15)]
// arr0: Wd2 (fwd)   arr1: Wd2^T (bwd)   arr2: We2   arr3: We3
__global__ __launch_bounds__(256)
void prep_kernel(const float* __restrict__ Wd2, const float* __restrict__ We2,
                 const float* __restrict__ We3, ushort* __restrict__ ws) {
  const int id = blockIdx.x * 256 + threadIdx.x;   // 65536 total
  const int arr = id >> 14;
  const int e = id & 16383;
  const int j = e & 7, L = (e >> 3) & 63, nt = (e >> 9) & 7, kc = e >> 12;
  const int kk = kc * 32 + (L >> 4) * 8 + j, nn = nt * 16 + (L & 15);
  float v;
  if      (arr == 0) v = Wd2[kk * HD + nn];
  else if (arr == 1) v = Wd2[nn * HD + kk];    // Wd2^T
  else if (arr == 2) v = We2[kk * HD + nn];
  else               v = We3[kk * HD + nn];
  ws[id] = (ushort)bfb(v);
}

__global__ __launch_bounds__(256, 4)
void metanets_kernel(
    const float* __restrict__ x_ctx, const float* __restrict__ y_ctx,
    const float* __restrict__ mask,  const float* __restrict__ z0,
    const float* __restrict__ noises,
    const float* __restrict__ We1, const float* __restrict__ be1,
    const float* __restrict__ be2, const float* __restrict__ be3,
    const float* __restrict__ Wd1, const float* __restrict__ bd1,
    const float* __restrict__ bd2, const float* __restrict__ Wd3,
    const float* __restrict__ bd3,
    const float* __restrict__ Wf1, const float* __restrict__ bf1,
    const float* __restrict__ Wf2, const float* __restrict__ bf2,
    const float* __restrict__ Wf3, const float* __restrict__ bf3,
    const ushort* __restrict__ wsfrag,
    float* __restrict__ out, int steps, float dt, float dco)
{
  // h1f doubles as the tau buffer (R7 invariant): within fwd/bwd every wave
  // touches only slots == w (mod 4) and A-frags are reg-loaded before the tau
  // scatter overwrites them.
  __shared__ unsigned int h1f[4096];    // A-frag units: [(slot)*64 + lane] x 4 dw
  __shared__ float zsh[64];
  __shared__ float zw1[128];
  __shared__ float rsh[128];
  __shared__ float dsumP[512];
  __shared__ float dsumC[128];
  __shared__ float f1sh[128];           // be2 staging, then drift hidden1
  __shared__ float f2sh[128];           // be3 staging, then drift hidden2
  __shared__ float bgz[128];            // f3 k-split partials (2x64)
  __shared__ float rw1sh[128];          // bf1 + r @ Wf1_r (step-invariant)
  __shared__ float wt1sh[128];          // Wf1 t-row staged
  __shared__ float bd2sh[128], wd3sh[128], wx0sh[128], wx1sh[128];

  const int tid = threadIdx.x;
  const int lane = tid & 63;                                  // context point
  const int w = __builtin_amdgcn_readfirstlane(tid >> 6);     // wave = m-tile
  const int b = blockIdx.x;
  const int rr = lane & 15, qq = lane >> 4;

  const bh8* Wd2f  = (const bh8*)(wsfrag);
  const bh8* Wd2Tf = (const bh8*)(wsfrag + 16384);
  const bh8* We2f  = (const bh8*)(wsfrag + 32768);
  const bh8* We3f  = (const bh8*)(wsfrag + 49152);

  const float x0v = x_ctx[(b*NPT + lane)*2 + 0];
  const float x1v = x_ctx[(b*NPT + lane)*2 + 1];
  const float yv  = y_ctx[b*NPT + lane];
  const float mkv = mask[b*NPT + lane];
  const float inv_msum = 1.0f / fmaxf(wsum64(mkv), 1e-6f);
  const float bd3v = bd3[0];

  // per-lane data for the 4 C-rows this lane holds (points 16w+4*qq+g)
  float x0q[4], x1q[4], yq[4], mkq[4];
  #pragma unroll
  for (int g = 0; g < 4; ++g) {
    const int src = (w << 4) | (qq << 2) | g;
    x0q[g] = __shfl(x0v, src, 64);
    x1q[g] = __shfl(x1v, src, 64);
    yq[g]  = __shfl(yv,  src, 64);
    mkq[g] = __shfl(mkv, src, 64);
  }

  if (tid < 64) zsh[tid] = z0[b*ZD + tid];
  if (tid < 128) {
    bd2sh[tid] = bd2[tid];
    wd3sh[tid] = Wd3[tid];
    wx0sh[tid] = Wd1[64*HD + tid];
    wx1sh[tid] = Wd1[65*HD + tid];
    f1sh[tid]  = be2[tid];
    f2sh[tid]  = be3[tid];
    wt1sh[tid] = Wf1[192*HD + tid];
  }
  __syncthreads();

  // ================= encoder =================
  // enc L1: lane=point, wave w computes k-slice kc=w, writes A-frag layout
  #pragma unroll
  for (int quad = 0; quad < 4; ++quad) {
    unsigned int pw[4];
    #pragma unroll
    for (int jj = 0; jj < 8; jj += 2) {
      const int k = 32*w + 8*quad + jj;
      const float sA = be1[k]   + x0v*We1[k]   + x1v*We1[HD+k]   + yv*We1[2*HD+k];
      const float sB = be1[k+1] + x0v*We1[k+1] + x1v*We1[HD+k+1] + yv*We1[2*HD+k+1];
      pw[jj>>1] = packbf(sA*sigf(sA), sB*sigf(sB));
    }
    uint4 v4; v4.x = pw[0]; v4.y = pw[1]; v4.z = pw[2]; v4.w = pw[3];
    ((uint4*)h1f)[(w*4 + (lane>>4))*64 + quad*16 + (lane&15)] = v4;
  }
  __syncthreads();

  // enc L2 (MFMA): H2 = silu(H1 @ We2 + be2) -> tau (A-frag layout, in h1f)
  // pair-processed: 8 B-frags + 2 accs live, immediate epilogue per nt.
  {
    bh8 af[4];
    #pragma unroll
    for (int kc = 0; kc < 4; ++kc)
      af[kc] = ((const bh8*)h1f)[(kc*4 + w)*64 + lane];
    #pragma unroll 1
    for (int np = 0; np < 4; ++np) {
      const int nt0 = 2*np, nt1 = 2*np + 1;
      const bh8 a0 = We2f[(0*8+nt0)*64 + lane];
      const bh8 a1 = We2f[(1*8+nt0)*64 + lane];
      const bh8 a2 = We2f[(2*8+nt0)*64 + lane];
      const bh8 a3 = We2f[(3*8+nt0)*64 + lane];
      const bh8 c0 = We2f[(0*8+nt1)*64 + lane];
      const bh8 c1 = We2f[(1*8+nt1)*64 + lane];
      const bh8 c2 = We2f[(2*8+nt1)*64 + lane];
      const bh8 c3 = We2f[(3*8+nt1)*64 + lane];
      const float bv0 = f1sh[nt0*16 + rr], bv1 = f1sh[nt1*16 + rr];
      fx4 acc0 = (fx4){bv0, bv0, bv0, bv0};
      fx4 acc1 = (fx4){bv1, bv1, bv1, bv1};
      acc0 = __builtin_amdgcn_mfma_f32_16x16x32_bf16(af[0], a0, acc0, 0,0,0);
      acc1 = __builtin_amdgcn_mfma_f32_16x16x32_bf16(af[0], c0, acc1, 0,0,0);
      acc0 = __builtin_amdgcn_mfma_f32_16x16x32_bf16(af[1], a1, acc0, 0,0,0);
      acc1 = __builtin_amdgcn_mfma_f32_16x16x32_bf16(af[1], c1, acc1, 0,0,0);
      acc0 = __builtin_amdgcn_mfma_f32_16x16x32_bf16(af[2], a2, acc0, 0,0,0);
      acc1 = __builtin_amdgcn_mfma_f32_16x16x32_bf16(af[2], c2, acc1, 0,0,0);
      acc0 = __builtin_amdgcn_mfma_f32_16x16x32_bf16(af[3], a3, acc0, 0,0,0);
      acc1 = __builtin_amdgcn_mfma_f32_16x16x32_bf16(af[3], c3, acc1, 0,0,0);
      #pragma unroll
      for (int pi = 0; pi < 2; ++pi) {
        const int nt = pi ? nt1 : nt0;
        const fx4 acc = pi ? acc1 : acc0;
        #pragma unroll
        for (int g = 0; g < 4; ++g) {
          const float s2 = acc[g];
          const unsigned int tb = bfb(s2 * sigf(s2));
          const unsigned int pb = (unsigned int)__shfl_xor((int)tb, 1, 64);
          if ((rr & 1) == 0) {
            const int unit = ((nt>>1)*4 + w)*64 + (2*(nt&1) + (rr>>3))*16 + 4*qq + g;
            h1f[unit*4 + ((rr&7)>>1)] = tb | (pb << 16);
          }
        }
      }
    }
  }
  wave_sync();

  // enc L3 (MFMA) + masked mean-pool -> rsh (pair-processed)
  {
    bh8 tf4[4];
    #pragma unroll
    for (int kc = 0; kc < 4; ++kc)
      tf4[kc] = ((const bh8*)h1f)[(kc*4 + w)*64 + lane];
    #pragma unroll 1
    for (int np = 0; np < 4; ++np) {
      const int nt0 = 2*np, nt1 = 2*np + 1;
      const bh8 a0 = We3f[(0*8+nt0)*64 + lane];
      const bh8 a1 = We3f[(1*8+nt0)*64 + lane];
      const bh8 a2 = We3f[(2*8+nt0)*64 + lane];
      const bh8 a3 = We3f[(3*8+nt0)*64 + lane];
      const bh8 c0 = We3f[(0*8+nt1)*64 + lane];
      const bh8 c1 = We3f[(1*8+nt1)*64 + lane];
      const bh8 c2 = We3f[(2*8+nt1)*64 + lane];
      const bh8 c3 = We3f[(3*8+nt1)*64 + lane];
      const float bv0 = f2sh[nt0*16 + rr], bv1 = f2sh[nt1*16 + rr];
      fx4 acc0 = (fx4){bv0, bv0, bv0, bv0};
      fx4 acc1 = (fx4){bv1, bv1, bv1, bv1};
      acc0 = __builtin_amdgcn_mfma_f32_16x16x32_bf16(tf4[0], a0, acc0, 0,0,0);
      acc1 = __builtin_amdgcn_mfma_f32_16x16x32_bf16(tf4[0], c0, acc1, 0,0,0);
      acc0 = __builtin_amdgcn_mfma_f32_16x16x32_bf16(tf4[1], a1, acc0, 0,0,0);
      acc1 = __builtin_amdgcn_mfma_f32_16x16x32_bf16(tf4[1], c1, acc1, 0,0,0);
      acc0 = __builtin_amdgcn_mfma_f32_16x16x32_bf16(tf4[2], a2, acc0, 0,0,0);
      acc1 = __builtin_amdgcn_mfma_f32_16x16x32_bf16(tf4[2], c2, acc1, 0,0,0);
      acc0 = __builtin_amdgcn_mfma_f32_16x16x32_bf16(tf4[3], a3, acc0, 0,0,0);
      acc1 = __builtin_amdgcn_mfma_f32_16x16x32_bf16(tf4[3], c3, acc1, 0,0,0);
      #pragma unroll
      for (int pi = 0; pi < 2; ++pi) {
        const int nt = pi ? nt1 : nt0;
        const fx4 acc = pi ? acc1 : acc0;
        float pv = mkq[0]*acc[0] + mkq[1]*acc[1]
                 + mkq[2]*acc[2] + mkq[3]*acc[3];
        pv += __shfl_xor(pv, 16, 64);
        pv += __shfl_xor(pv, 32, 64);
        if (lane < 16) dsumP[w*128 + nt*16 + lane] = pv;
      }
    }
  }
  __syncthreads();
  if (tid < 128)
    rsh[tid] = (dsumP[tid] + dsumP[128+tid] + dsumP[256+tid] + dsumP[384+tid]) * inv_msum;
  __syncthreads();

  // rW1 precompute (once): rw1sh = bf1 + r @ Wf1_r  (step-invariant part of f1)
  if (tid < 128) {
    float p0 = bf1[tid], p1 = 0.f, p2 = 0.f, p3 = 0.f;
    #pragma unroll 4
    for (int j = 0; j < 128; j += 4) {
      p0 = fmaf(rsh[j+0], Wf1[(64+j+0)*HD + tid], p0);
      p1 = fmaf(rsh[j+1], Wf1[(64+j+1)*HD + tid], p1);
      p2 = fmaf(rsh[j+2], Wf1[(64+j+2)*HD + tid], p2);
      p3 = fmaf(rsh[j+3], Wf1[(64+j+3)*HD + tid], p3);
    }
    rw1sh[tid] = (p0+p1) + (p2+p3);
  }
  __syncthreads();

  // ================= Langevin step loop =================
  for (int st = 0; st < steps; ++st) {
    const float t = (float)st * dt;
    const int zi = tid & 63;

    // noise + zold read at step top by ALL lanes. zsh is stable from here
    // until the post-B5 update (only same-value late writes from the previous
    // update can be in flight) — this kills the R11 RMW race.
    const float noise_v = noises[(size_t)st * (B_TOT * ZD) + b * ZD + zi];
    const float zold_r  = zsh[zi];

    // ---- A: t<128: zw1  ||  t>=128: f1 (both 64-fmaf matvecs, balanced)
    if (tid < 128) {
      float p0 = bd1[tid], p1 = 0.f, p2 = 0.f, p3 = 0.f;
      #pragma unroll 4
      for (int j = 0; j < 64; j += 4) {
        p0 = fmaf(zsh[j+0], Wd1[(j+0)*HD + tid], p0);
        p1 = fmaf(zsh[j+1], Wd1[(j+1)*HD + tid], p1);
        p2 = fmaf(zsh[j+2], Wd1[(j+2)*HD + tid], p2);
        p3 = fmaf(zsh[j+3], Wd1[(j+3)*HD + tid], p3);
      }
      zw1[tid] = (p0+p1) + (p2+p3);
    } else {
      const int o = tid - 128;
      float p0 = fmaf(t, wt1sh[o], rw1sh[o]);
      float p1 = 0.f, p2 = 0.f, p3 = 0.f;
      #pragma unroll 4
      for (int j = 0; j < 64; j += 4) {
        p0 = fmaf(zsh[j+0], Wf1[(j+0)*HD + o], p0);
        p1 = fmaf(zsh[j+1], Wf1[(j+1)*HD + o], p1);
        p2 = fmaf(zsh[j+2], Wf1[(j+2)*HD + o], p2);
        p3 = fmaf(zsh[j+3], Wf1[(j+3)*HD + o], p3);
      }
      const float a = (p0+p1) + (p2+p3);
      f1sh[o] = a * sigf(a);
    }
    __syncthreads();   // B0: zw1 + f1sh ready

    // ---- B: dec L1 on ALL 4 waves (kc = w), ~150 ops/lane
    #pragma unroll
    for (int quad = 0; quad < 4; ++quad) {
      unsigned int pw[4];
      #pragma unroll
      for (int jj = 0; jj < 8; jj += 2) {
        const int k = 32*w + 8*quad + jj;
        const float sA = zw1[k]   + x0v*wx0sh[k]   + x1v*wx1sh[k];
        const float sB = zw1[k+1] + x0v*wx0sh[k+1] + x1v*wx1sh[k+1];
        pw[jj>>1] = packbf(sA*sigf(sA), sB*sigf(sB));
      }
      uint4 v4; v4.x = pw[0]; v4.y = pw[1]; v4.z = pw[2]; v4.w = pw[3];
      ((uint4*)h1f)[(w*4 + (lane>>4))*64 + quad*16 + (lane&15)] = v4;
    }
    __syncthreads();   // B1: h1f (all kc slices) ready

    // fwd (MFMA): S2 = H1 @ Wd2 + bd2; emit tau (-> h1f, wave-private slots)
    // pair-processed: 8 B-frags + 2 accs live.
    float ebw[4];
    {
      bh8 af[4];
      #pragma unroll
      for (int kc = 0; kc < 4; ++kc)
        af[kc] = ((const bh8*)h1f)[(kc*4 + w)*64 + lane];
      float da[4] = {0.f, 0.f, 0.f, 0.f};
      #pragma unroll 1
      for (int np = 0; np < 4; ++np) {
        const int nt0 = 2*np, nt1 = 2*np + 1;
        const bh8 a0 = Wd2f[(0*8+nt0)*64 + lane];
        const bh8 a1 = Wd2f[(1*8+nt0)*64 + lane];
        const bh8 a2 = Wd2f[(2*8+nt0)*64 + lane];
        const bh8 a3 = Wd2f[(3*8+nt0)*64 + lane];
        const bh8 c0 = Wd2f[(0*8+nt1)*64 + lane];
        const bh8 c1 = Wd2f[(1*8+nt1)*64 + lane];
        const bh8 c2 = Wd2f[(2*8+nt1)*64 + lane];
        const bh8 c3 = Wd2f[(3*8+nt1)*64 + lane];
        const float bv0 = bd2sh[nt0*16 + rr], bv1 = bd2sh[nt1*16 + rr];
        fx4 acc0 = (fx4){bv0, bv0, bv0, bv0};
        fx4 acc1 = (fx4){bv1, bv1, bv1, bv1};
        acc0 = __builtin_amdgcn_mfma_f32_16x16x32_bf16(af[0], a0, acc0, 0,0,0);
        acc1 = __builtin_amdgcn_mfma_f32_16x16x32_bf16(af[0], c0, acc1, 0,0,0);
        acc0 = __builtin_amdgcn_mfma_f32_16x16x32_bf16(af[1], a1, acc0, 0,0,0);
        acc1 = __builtin_amdgcn_mfma_f32_16x16x32_bf16(af[1], c1, acc1, 0,0,0);
        acc0 = __builtin_amdgcn_mfma_f32_16x16x32_bf16(af[2], a2, acc0, 0,0,0);
        acc1 = __builtin_amdgcn_mfma_f32_16x16x32_bf16(af[2], c2, acc1, 0,0,0);
        acc0 = __builtin_amdgcn_mfma_f32_16x16x32_bf16(af[3], a3, acc0, 0,0,0);
        acc1 = __builtin_amdgcn_mfma_f32_16x16x32_bf16(af[3], c3, acc1, 0,0,0);
        #pragma unroll
        for (int pi = 0; pi < 2; ++pi) {
          const int nt = pi ? nt1 : nt0;
          const fx4 acc = pi ? acc1 : acc0;
          const float w3 = wd3sh[nt*16 + rr];
          #pragma unroll
          for (int g = 0; g < 4; ++g) {
            const float s2 = acc[g];
            const float sg = sigf(s2);
            da[g] = fmaf(s2*sg, w3, da[g]);
            const unsigned int tb = bfb(w3 * (sg * fmaf(s2, 1.0f - sg, 1.0f)));
            const unsigned int pb = (unsigned int)__shfl_xor((int)tb, 1, 64);
            if ((rr & 1) == 0) {
              const int unit = ((nt>>1)*4 + w)*64 + (2*(nt&1) + (rr>>3))*16 + 4*qq + g;
              h1f[unit*4 + ((rr&7)>>1)] = tb | (pb << 16);
            }
          }
        }
      }
      #pragma unroll
      for (int g = 0; g < 4; ++g) {
        float v = da[g];
        v += __shfl_xor(v, 1, 64);
        v += __shfl_xor(v, 2, 64);
        v += __shfl_xor(v, 4, 64);
        v += __shfl_xor(v, 8, 64);
        ebw[g] = t * mkq[g] * (v + bd3v - yq[g]);
      }
    }
    wave_sync();

    // bwd (MFMA): U = TAU @ Wd2^T; dsum[k] = colsum(ebw * silu'(s1) * U)
    // pair-processed.
    {
      bh8 tf4[4];
      #pragma unroll
      for (int kc = 0; kc < 4; ++kc)
        tf4[kc] = ((const bh8*)h1f)[(kc*4 + w)*64 + lane];
      #pragma unroll 1
      for (int np = 0; np < 4; ++np) {
        const int nt0 = 2*np, nt1 = 2*np + 1;
        const bh8 a0 = Wd2Tf[(0*8+nt0)*64 + lane];
        const bh8 a1 = Wd2Tf[(1*8+nt0)*64 + lane];
        const bh8 a2 = Wd2Tf[(2*8+nt0)*64 + lane];
        const bh8 a3 = Wd2Tf[(3*8+nt0)*64 + lane];
        const bh8 c0 = Wd2Tf[(0*8+nt1)*64 + lane];
        const bh8 c1 = Wd2Tf[(1*8+nt1)*64 + lane];
        const bh8 c2 = Wd2Tf[(2*8+nt1)*64 + lane];
        const bh8 c3 = Wd2Tf[(3*8+nt1)*64 + lane];
        fx4 u0 = (fx4){0.f, 0.f, 0.f, 0.f};
        fx4 u1 = (fx4){0.f, 0.f, 0.f, 0.f};
        u0 = __builtin_amdgcn_mfma_f32_16x16x32_bf16(tf4[0], a0, u0, 0,0,0);
        u1 = __builtin_amdgcn_mfma_f32_16x16x32_bf16(tf4[0], c0, u1, 0,0,0);
        u0 = __builtin_amdgcn_mfma_f32_16x16x32_bf16(tf4[1], a1, u0, 0,0,0);
        u1 = __builtin_amdgcn_mfma_f32_16x16x32_bf16(tf4[1], c1, u1, 0,0,0);
        u0 = __builtin_amdgcn_mfma_f32_16x16x32_bf16(tf4[2], a2, u0, 0,0,0);
        u1 = __builtin_amdgcn_mfma_f32_16x16x32_bf16(tf4[2], c2, u1, 0,0,0);
        u0 = __builtin_amdgcn_mfma_f32_16x16x32_bf16(tf4[3], a3, u0, 0,0,0);
        u1 = __builtin_amdgcn_mfma_f32_16x16x32_bf16(tf4[3], c3, u1, 0,0,0);
        #pragma unroll
        for (int pi = 0; pi < 2; ++pi) {
          const int nt = pi ? nt1 : nt0;
          const fx4 u = pi ? u1 : u0;
          const float zv = zw1[nt*16 + rr];
          const float wa = wx0sh[nt*16 + rr];
          const float wb = wx1sh[nt*16 + rr];
          float snt = 0.f;
          #pragma unroll
          for (int g = 0; g < 4; ++g) {
            const float s1 = zv + x0q[g]*wa + x1q[g]*wb;
            const float sg = sigf(s1);
            snt += ebw[g] * (sg * fmaf(s1, 1.0f - sg, 1.0f)) * u[g];
          }
          snt += __shfl_xor(snt, 16, 64);
          snt += __shfl_xor(snt, 32, 64);
          if (lane < 16) dsumP[w*128 + nt*16 + lane] = snt;
        }
      }
    }
    __syncthreads();   // B3: dsumP ready

    // ---- S3: tid<128: dsumC combine  ||  tid>=128: f2
    if (tid < 128) {
      dsumC[tid] = dsumP[tid] + dsumP[128+tid] + dsumP[256+tid] + dsumP[384+tid];
    } else {
      const int o = tid - 128;
      float p0 = bf2[o], p1 = 0.f, p2 = 0.f, p3 = 0.f;
      #pragma unroll 4
      for (int j = 0; j < 128; j += 4) {
        p0 = fmaf(f1sh[j+0], Wf2[(j+0)*HD + o], p0);
        p1 = fmaf(f1sh[j+1], Wf2[(j+1)*HD + o], p1);
        p2 = fmaf(f1sh[j+2], Wf2[(j+2)*HD + o], p2);
        p3 = fmaf(f1sh[j+3], Wf2[(j+3)*HD + o], p3);
      }
      const float a = (p0+p1) + (p2+p3);
      f2sh[o] = a * sigf(a);
    }
    // S3->S4 hand-off is wave-aligned: wave0/1 read own dsumC half; wave2/3
    // read own f2sh half. wave_sync suffices (no cross-wave reads).
    wave_sync();

    // ---- S4 (2-way k-splits): tid<128: gz halves || tid>=128: f3 halves
    if (tid < 128) {
      const int j = tid & 63, h0 = (tid >> 6) * 64;
      float p0 = 0.f, p1 = 0.f, p2 = 0.f, p3 = 0.f;
      #pragma unroll 4
      for (int h = 0; h < 64; h += 4) {
        p0 = fmaf(dsumC[h0+h+0], Wd1[j*HD + h0+h+0], p0);
        p1 = fmaf(dsumC[h0+h+1], Wd1[j*HD + h0+h+1], p1);
        p2 = fmaf(dsumC[h0+h+2], Wd1[j*HD + h0+h+2], p2);
        p3 = fmaf(dsumC[h0+h+3], Wd1[j*HD + h0+h+3], p3);
      }
      dsumP[tid] = (p0+p1) + (p2+p3);            // gz partials (t in ebw)
    } else {
      const int o = tid - 128;
      const int j = o & 63, h0 = (o >> 6) * 64;
      float p0 = (h0 == 0) ? bf3[j] : 0.f;
      float p1 = 0.f, p2 = 0.f, p3 = 0.f;
      #pragma unroll 4
      for (int h = 0; h < 64; h += 4) {
        p0 = fmaf(f2sh[h0+h+0], Wf3[(h0+h+0)*ZD + j], p0);
        p1 = fmaf(f2sh[h0+h+1], Wf3[(h0+h+1)*ZD + j], p1);
        p2 = fmaf(f2sh[h0+h+2], Wf3[(h0+h+2)*ZD + j], p2);
        p3 = fmaf(f2sh[h0+h+3], Wf3[(h0+h+3)*ZD + j], p3);
      }
      bgz[o] = (p0+p1) + (p2+p3);                // f3 partials
    }
    __syncthreads();   // B5: partials ready (cross-wave reads next)

    // ---- update: computed redundantly by ALL 4 waves. zold comes from the
    // step-top REGISTER (no LDS read here) -> writes are pure same-value
    // stores; wave_sync suffices afterwards.
    {
      const float bdrift = bgz[zi] + bgz[64 + zi];
      const float gzv    = dsumP[zi] + dsumP[64 + zi];
      float g = zold_r + gzv;
      g = fminf(fmaxf(g, -100.0f), 100.0f);
      zsh[zi] = zold_r + (bdrift - g) * dt + dco * noise_v;
    }
    wave_sync();       // own-wave zsh writes drained; next step reads own copy
  }

  if (tid < 64) out[b * ZD + tid] = zsh[tid];
}

extern "C" void kernel_launch(void* const* d_in, const int* in_sizes, int n_in,
                              void* d_out, int out_size, void* d_ws, size_t ws_size,
                              hipStream_t stream) {
  const float* x_ctx  = (const float*)d_in[0];
  const float* y_ctx  = (const float*)d_in[1];
  const float* mask   = (const float*)d_in[2];
  const float* z0     = (const float*)d_in[3];
  const float* noises = (const float*)d_in[4];
  const float* We1 = (const float*)d_in[5];  const float* be1 = (const float*)d_in[6];
  const float* We2 = (const float*)d_in[7];  const float* be2 = (const float*)d_in[8];
  const float* We3 = (const float*)d_in[9];  const float* be3 = (const float*)d_in[10];
  const float* Wd1 = (const float*)d_in[11]; const float* bd1 = (const float*)d_in[12];
  const float* Wd2 = (const float*)d_in[13]; const float* bd2 = (const float*)d_in[14];
  const float* Wd3 = (const float*)d_in[15]; const float* bd3 = (const float*)d_in[16];
  const float* Wf1 = (const float*)d_in[17]; const float* bf1 = (const float*)d_in[18];
  const float* Wf2 = (const float*)d_in[19]; const float* bf2 = (const float*)d_in[20];
  const float* Wf3 = (const float*)d_in[21]; const float* bf3 = (const float*)d_in[22];

  const int steps = in_sizes[4] / (B_TOT * ZD);
  const float dt  = 1.0f / (float)steps;
  const float dco = (float)sqrt(2.0 / (double)steps);

  ushort* wsu = (ushort*)d_ws;   // 4 bf16 frag arrays, 128 KB total

  hipLaunchKernelGGL(prep_kernel, dim3(256), dim3(256), 0, stream, Wd2, We2, We3, wsu);
  hipLaunchKernelGGL(metanets_kernel, dim3(B_TOT), dim3(256), 0, stream,
      x_ctx, y_ctx, mask, z0, noises,
      We1, be1, be2, be3,
      Wd1, bd1, bd2, Wd3, bd3,
      Wf1, bf1, Wf2, bf2, Wf3, bf3,
      wsu, (float*)d_out, steps, dt, dco);
}